// Round 8
// baseline (847.176 us; speedup 1.0000x reference)
//
#include <hip/hip_runtime.h>
#include <hip/hip_bf16.h>

// EGNN encoder, N=50000, E=250000, D=128, L=4. bf16 inputs/output (verified R2).
// R3: CSR-by-tgt aggregation (no atomics), EW2@NW1b folding.
// R4: 3-stage parallel CSR scan.  R5: agg chunked x4 + fast rcp.
// R6: mega-fusion REGRESSED -> reverted.
// R7: weight-stationary streaming matmuls (LDS-staged weights, grid-stride).
// R8: agg transposed: 16 lanes/edge x 4 edges/wave -> 4-step in-group butterfly
//     (4 DS/chunk vs 24), parallel per-edge scalar MLP, bf16x8 A-gather.

#define NNODES 50000
#define NEDGES 250000
#define NTILES 3125   // 50000/16 exactly, no tail
#define MMGRID 512

typedef unsigned short u16;
typedef __attribute__((ext_vector_type(8))) short bf16x8;
typedef __attribute__((ext_vector_type(4))) float floatx4;

__device__ __forceinline__ float b2f(u16 h){ unsigned u=((unsigned)h)<<16; float f; __builtin_memcpy(&f,&u,4); return f; }
__device__ __forceinline__ u16 f2b(float f){ unsigned u; __builtin_memcpy(&u,&f,4); u = u + 0x7FFFu + ((u>>16)&1u); return (u16)(u>>16); }
__device__ __forceinline__ float siluf(float x){ return x*__builtin_amdgcn_rcpf(1.f+__expf(-x)); }
__device__ __forceinline__ float ldf(const void* p, long i, int isbf){
  return isbf ? b2f(((const u16*)p)[i]) : ((const float*)p)[i];
}
__device__ __forceinline__ void ld8bf(const u16* p, float* o){
  bf16x8 v = *(const bf16x8*)p;
  u16 tmp[8]; __builtin_memcpy(tmp, &v, 16);
#pragma unroll
  for (int j=0;j<8;j++) o[j] = b2f(tmp[j]);
}

__global__ void detect_kernel(const void* lng, int* flag){
  if (threadIdx.x==0 && blockIdx.x==0) *flag = (((const u16*)lng)[0] != 0) ? 1 : 0;
}

// ---------- weight packing into MFMA B-fragment order (24 input matrices) ----------
__global__ __launch_bounds__(256) void pack_kernel(
    const void* __restrict__ ew1, const void* __restrict__ ew2,
    const void* __restrict__ nw1, const void* __restrict__ nw2,
    u16* __restrict__ packed, const int* __restrict__ flagp)
{
  const int isbf = *flagp;
  int t = blockIdx.x*256 + threadIdx.x;       // 24 * 2048
  int m = t >> 11; int r = t & 2047;
  int lane = r & 63; int ntk = r >> 6;
  int kk = ntk >> 3, nt = ntk & 7;
  int l = m/6, w = m%6;
  const void* src; long off;
  switch(w){
    case 0: src=ew1; off=(long)l*257*128;            break; // W1a
    case 1: src=ew1; off=(long)l*257*128 + 128*128;  break; // W1b
    case 2: src=ew2; off=(long)l*128*128;            break; // EW2
    case 3: src=nw1; off=(long)l*256*128;            break; // NW1a
    case 4: src=nw1; off=(long)l*256*128 + 128*128;  break; // NW1b
    default:src=nw2; off=(long)l*128*128;            break; // NW2
  }
  int c  = nt*16 + (lane & 15);
  int k0 = kk*32 + (lane >> 4)*8;
  u16 vals[8];
#pragma unroll
  for (int j=0;j<8;j++){
    long idx = off + (long)(k0+j)*128 + c;
    vals[j] = isbf ? ((const u16*)src)[idx] : f2b(((const float*)src)[idx]);
  }
  bf16x8 v; __builtin_memcpy(&v, vals, 16);
  *(bf16x8*)(packed + (long)t*8) = v;
}

// ---------- pack fp32 W12[l] (4 matrices) into chunks 24..27 ----------
__global__ __launch_bounds__(256) void pack2_kernel(
    const float* __restrict__ W12f, u16* __restrict__ packed)
{
  int t = blockIdx.x*256 + threadIdx.x;       // 4 * 2048
  int m = t >> 11; int r = t & 2047;
  int lane = r & 63; int ntk = r >> 6;
  int kk = ntk >> 3, nt = ntk & 7;
  const float* base = W12f + (long)m*16384;
  int c  = nt*16 + (lane & 15);
  int k0 = kk*32 + (lane >> 4)*8;
  u16 vals[8];
#pragma unroll
  for (int j=0;j<8;j++) vals[j] = f2b(base[(long)(k0+j)*128 + c]);
  bf16x8 v; __builtin_memcpy(&v, vals, 16);
  *(bf16x8*)(packed + ((long)(24+m)*2048 + r)*8) = v;
}

// ---------- W12[l][k][j] = sum_d EW2[l][k][d]*NW1b[l][d][j] (fp32) ----------
__global__ __launch_bounds__(128) void w12_kernel(
    const void* __restrict__ ew2, const void* __restrict__ nw1,
    float* __restrict__ W12f, const int* __restrict__ flagp)
{
  const int isbf = *flagp;
  int l = blockIdx.x >> 7, k = blockIdx.x & 127, j = threadIdx.x;
  long e2 = (long)l*16384 + (long)k*128;
  long nb = (long)l*256*128 + 128*128;
  float acc = 0.f;
  for (int d=0; d<128; d++)
    acc += ldf(ew2, e2 + d, isbf) * ldf(nw1, nb + (long)d*128 + j, isbf);
  W12f[(long)l*16384 + (long)k*128 + j] = acc;
}

// ---------- ebW[l][j] = sum_d eb2[l][d]*NW1b[l][d][j] ----------
__global__ __launch_bounds__(128) void ebw_kernel(
    const void* __restrict__ eb2, const void* __restrict__ nw1,
    float* __restrict__ ebW, const int* __restrict__ flagp)
{
  const int isbf = *flagp;
  int l = blockIdx.x, j = threadIdx.x;
  long nb = (long)l*256*128 + 128*128;
  float acc = 0.f;
  for (int d=0; d<128; d++)
    acc += ldf(eb2, (long)l*128 + d, isbf) * ldf(nw1, nb + (long)d*128 + j, isbf);
  ebW[l*128+j] = acc;
}

// ---------- per-layer w2p = EW2 @ pw1[0:128], c2p = eb2 . pw1[0:128] ----------
__global__ __launch_bounds__(128) void w2p_kernel(
    const void* __restrict__ ew2, const void* __restrict__ eb2, const void* __restrict__ pw1,
    float* __restrict__ w2p, float* __restrict__ c2p, const int* __restrict__ flagp)
{
  const int isbf = *flagp;
  int l = blockIdx.x, i = threadIdx.x;
  long Woff = (long)l*128*128, poff = (long)l*129;
  float acc = 0.f;
  for (int j=0;j<128;j++) acc += ldf(ew2, Woff + (long)i*128 + j, isbf) * ldf(pw1, poff + j, isbf);
  w2p[l*128+i] = acc;
  __shared__ float red[128];
  red[i] = ldf(eb2, (long)l*128 + i, isbf) * ldf(pw1, poff + i, isbf);
  __syncthreads();
  for (int st=64; st>0; st>>=1){ if (i<st) red[i]+=red[i+st]; __syncthreads(); }
  if (i==0) c2p[l] = red[0];
}

__global__ void pparm_kernel(const void* pw1, const void* pb1, const void* pw2, const void* pb2,
                             float* pparm, const int* flagp)
{
  const int isbf = *flagp;
  int l = threadIdx.x;
  if (l < 4){
    pparm[l*4+0] = ldf(pw1, (long)l*129 + 128, isbf);
    pparm[l*4+1] = ldf(pb1, l, isbf);
    pparm[l*4+2] = ldf(pw2, l, isbf);
    pparm[l*4+3] = ldf(pb2, l, isbf);
  }
}

// ---------- CSR build: histogram, 3-stage scan, scatter ----------
__global__ __launch_bounds__(256) void hist_kernel(const int* __restrict__ tgt, int* __restrict__ cnt, int E){
  int i = blockIdx.x*256 + threadIdx.x;
  if (i < E) atomicAdd(&cnt[tgt[i]], 1);
}

__global__ __launch_bounds__(256) void bsum_kernel(const int* __restrict__ cnt, int* __restrict__ bsum, int N){
  int i = blockIdx.x*256 + threadIdx.x;
  int v = (i < N) ? cnt[i] : 0;
#pragma unroll
  for (int off=32; off; off>>=1) v += __shfl_down(v, off);
  __shared__ int ws[4];
  if ((threadIdx.x & 63) == 0) ws[threadIdx.x>>6] = v;
  __syncthreads();
  if (threadIdx.x == 0) bsum[blockIdx.x] = ws[0]+ws[1]+ws[2]+ws[3];
}

__global__ __launch_bounds__(256) void bscan_kernel(int* __restrict__ bsum, int nb){
  __shared__ int lds[256];
  int i = threadIdx.x;
  int v = (i < nb) ? bsum[i] : 0;
  lds[i] = v; __syncthreads();
#pragma unroll
  for (int off=1; off<256; off<<=1){
    int t = (i>=off)? lds[i-off] : 0; __syncthreads();
    lds[i] += t; __syncthreads();
  }
  if (i < nb) bsum[i] = lds[i] - v;  // exclusive prefix
}

__global__ __launch_bounds__(256) void csr_kernel(
    const int* __restrict__ cnt, const int* __restrict__ bsum,
    int* __restrict__ rowptr, int* __restrict__ cursor, float* __restrict__ degf, int N)
{
  __shared__ int lds[256];
  int i = blockIdx.x*256 + threadIdx.x;
  int c = (i < N) ? cnt[i] : 0;
  lds[threadIdx.x] = c; __syncthreads();
#pragma unroll
  for (int off=1; off<256; off<<=1){
    int t = (threadIdx.x>=off)? lds[threadIdx.x-off] : 0; __syncthreads();
    lds[threadIdx.x] += t; __syncthreads();
  }
  int run = bsum[blockIdx.x] + lds[threadIdx.x] - c;  // exclusive
  if (i < N){
    rowptr[i] = run; cursor[i] = run; degf[i] = (float)c;
    if (i == N-1) rowptr[N] = run + c;
  }
}

__global__ __launch_bounds__(256) void scatter_kernel(
    const int* __restrict__ src, const int* __restrict__ tgt,
    int* __restrict__ cursor, int* __restrict__ permsrc, int E)
{
  int e = blockIdx.x*256 + threadIdx.x;
  if (e >= E) return;
  int t = tgt[e];
  int p = atomicAdd(&cursor[t], 1);
  permsrc[p] = src[e];
}

// ---------- initial projection x = nf @ npw + npb (2 nodes/block) ----------
__global__ __launch_bounds__(256) void proj_kernel(
    const void* __restrict__ nf, const void* __restrict__ W, const void* __restrict__ bvec,
    float* __restrict__ xf, u16* __restrict__ xb, int N, const int* __restrict__ flagp)
{
  const int isbf = *flagp;
  int n = blockIdx.x*2 + (threadIdx.x>>7), d = threadIdx.x & 127;
  if (n >= N) return;
  float acc = ldf(bvec, d, isbf);
#pragma unroll
  for (int f=0; f<12; f++) acc += ldf(nf, (long)n*12+f, isbf) * ldf(W, f*128+d, isbf);
  xf[(long)n*128+d] = acc;
  xb[(long)n*128+d] = f2b(acc);
}

__global__ __launch_bounds__(256) void cvtp_kernel(const void* __restrict__ pos, float* __restrict__ pf,
                                                   int n, const int* __restrict__ flagp){
  const int isbf = *flagp;
  int i = blockIdx.x*256 + threadIdx.x;
  if (i < n) pf[i] = ldf(pos, i, isbf);
}

// ---------- streaming A/B matmul: Ab = bf16(x@Wa+eb1), Bb = bf16(x@Wb) ----------
__global__ __launch_bounds__(256) void mm_ab_kernel(
    const u16* __restrict__ X, const u16* __restrict__ Wa, const u16* __restrict__ Wb,
    const void* __restrict__ bias, long bias_off,
    u16* __restrict__ Ab, u16* __restrict__ Bb, const int* __restrict__ flagp)
{
  extern __shared__ u16 wlds[];
  const int tid = threadIdx.x, wave = tid>>6, lane = tid&63;
  const int isbf = *flagp;
  const int lr = lane&15, lg = lane>>4;
  for (int i=tid; i<2048; i+=256){
    *(bf16x8*)(wlds + (long)i*8)          = *(const bf16x8*)(Wa + (long)i*8);
    *(bf16x8*)(wlds + 16384 + (long)i*8)  = *(const bf16x8*)(Wb + (long)i*8);
  }
  float biasv[8];
#pragma unroll
  for (int nt=0;nt<8;nt++) biasv[nt] = ldf(bias, bias_off + nt*16 + lr, isbf);
  __syncthreads();
  for (int tile = blockIdx.x*4 + wave; tile < NTILES; tile += MMGRID*4){
    const u16* xr = X + ((long)tile*16 + lr)*128;
    bf16x8 a[4];
#pragma unroll
    for (int kk=0;kk<4;kk++) a[kk] = *(const bf16x8*)(xr + kk*32 + lg*8);
    floatx4 accA[8], accB[8];
#pragma unroll
    for (int i=0;i<8;i++){ accA[i]=(floatx4){0,0,0,0}; accB[i]=(floatx4){0,0,0,0}; }
#pragma unroll
    for (int kk=0;kk<4;kk++){
#pragma unroll
      for (int nt=0;nt<8;nt++){
        bf16x8 ba = *(const bf16x8*)(wlds + ((kk*8+nt)*64 + lane)*8);
        accA[nt] = __builtin_amdgcn_mfma_f32_16x16x32_bf16(a[kk], ba, accA[nt], 0, 0, 0);
        bf16x8 bb = *(const bf16x8*)(wlds + 16384 + ((kk*8+nt)*64 + lane)*8);
        accB[nt] = __builtin_amdgcn_mfma_f32_16x16x32_bf16(a[kk], bb, accB[nt], 0, 0, 0);
      }
    }
#pragma unroll
    for (int r=0;r<4;r++){
      long row = (long)tile*16 + lg*4 + r;
#pragma unroll
      for (int nt=0;nt<8;nt++){
        int col = nt*16 + lr;
        Ab[row*128+col] = f2b(accA[nt][r] + biasv[nt]);
        Bb[row*128+col] = f2b(accB[nt][r]);
      }
    }
  }
}

// ---------- streaming hidden matmul: hb = bf16(silu(xb@NW1a + Hb@W12 + deg*ebW + nb1)) ----------
__global__ __launch_bounds__(256) void mm_hidden_kernel(
    const u16* __restrict__ X, const u16* __restrict__ H,
    const u16* __restrict__ W1, const u16* __restrict__ W2,
    const void* __restrict__ nb1, long nb1_off,
    const float* __restrict__ degf, const float* __restrict__ ebW,
    u16* __restrict__ hb, const int* __restrict__ flagp)
{
  extern __shared__ u16 wlds[];
  const int tid = threadIdx.x, wave = tid>>6, lane = tid&63;
  const int isbf = *flagp;
  const int lr = lane&15, lg = lane>>4;
  for (int i=tid; i<2048; i+=256){
    *(bf16x8*)(wlds + (long)i*8)          = *(const bf16x8*)(W1 + (long)i*8);
    *(bf16x8*)(wlds + 16384 + (long)i*8)  = *(const bf16x8*)(W2 + (long)i*8);
  }
  float nb1v[8], ebv[8];
#pragma unroll
  for (int nt=0;nt<8;nt++){ int col=nt*16+lr; nb1v[nt]=ldf(nb1, nb1_off+col, isbf); ebv[nt]=ebW[col]; }
  __syncthreads();
  for (int tile = blockIdx.x*4 + wave; tile < NTILES; tile += MMGRID*4){
    const u16* xr = X + ((long)tile*16 + lr)*128;
    const u16* hr = H + ((long)tile*16 + lr)*128;
    bf16x8 ax[4], ah[4];
#pragma unroll
    for (int kk=0;kk<4;kk++){
      ax[kk] = *(const bf16x8*)(xr + kk*32 + lg*8);
      ah[kk] = *(const bf16x8*)(hr + kk*32 + lg*8);
    }
    floatx4 acc[8];
#pragma unroll
    for (int i=0;i<8;i++) acc[i]=(floatx4){0,0,0,0};
#pragma unroll
    for (int kk=0;kk<4;kk++){
#pragma unroll
      for (int nt=0;nt<8;nt++){
        bf16x8 b1 = *(const bf16x8*)(wlds + ((kk*8+nt)*64 + lane)*8);
        acc[nt] = __builtin_amdgcn_mfma_f32_16x16x32_bf16(ax[kk], b1, acc[nt], 0, 0, 0);
        bf16x8 b2 = *(const bf16x8*)(wlds + 16384 + ((kk*8+nt)*64 + lane)*8);
        acc[nt] = __builtin_amdgcn_mfma_f32_16x16x32_bf16(ah[kk], b2, acc[nt], 0, 0, 0);
      }
    }
    float dv[4];
#pragma unroll
    for (int r=0;r<4;r++) dv[r] = degf[(long)tile*16 + lg*4 + r];
#pragma unroll
    for (int r=0;r<4;r++){
      long row = (long)tile*16 + lg*4 + r;
#pragma unroll
      for (int nt=0;nt<8;nt++){
        int col = nt*16 + lr;
        hb[row*128+col] = f2b(siluf(acc[nt][r] + nb1v[nt] + dv[r]*ebv[nt]));
      }
    }
  }
}

// ---------- streaming residual matmul: xnew = xf + hb@NW2 + nb2 ----------
template<int LN>
__global__ __launch_bounds__(256) void mm_res_kernel(
    const u16* __restrict__ H, const u16* __restrict__ W,
    const void* __restrict__ nb2, long nb2_off,
    float* __restrict__ xf, u16* __restrict__ xb,
    const void* __restrict__ lng, const void* __restrict__ lnb, void* __restrict__ outp,
    const int* __restrict__ flagp)
{
  extern __shared__ u16 wlds[];
  const int tid = threadIdx.x, wave = tid>>6, lane = tid&63;
  const int isbf = *flagp;
  const int lr = lane&15, lg = lane>>4;
  for (int i=tid; i<2048; i+=256)
    *(bf16x8*)(wlds + (long)i*8) = *(const bf16x8*)(W + (long)i*8);
  float nb2v[8];
#pragma unroll
  for (int nt=0;nt<8;nt++) nb2v[nt] = ldf(nb2, nb2_off + nt*16 + lr, isbf);
  float gv[8], bvv[8];
  if (LN){
#pragma unroll
    for (int nt=0;nt<8;nt++){ int col=nt*16+lr; gv[nt]=ldf(lng,col,isbf); bvv[nt]=ldf(lnb,col,isbf); }
  }
  __syncthreads();
  for (int tile = blockIdx.x*4 + wave; tile < NTILES; tile += MMGRID*4){
    const u16* hr = H + ((long)tile*16 + lr)*128;
    bf16x8 a[4];
#pragma unroll
    for (int kk=0;kk<4;kk++) a[kk] = *(const bf16x8*)(hr + kk*32 + lg*8);
    floatx4 acc[8];
#pragma unroll
    for (int i=0;i<8;i++) acc[i]=(floatx4){0,0,0,0};
#pragma unroll
    for (int kk=0;kk<4;kk++){
#pragma unroll
      for (int nt=0;nt<8;nt++){
        bf16x8 b = *(const bf16x8*)(wlds + ((kk*8+nt)*64 + lane)*8);
        acc[nt] = __builtin_amdgcn_mfma_f32_16x16x32_bf16(a[kk], b, acc[nt], 0, 0, 0);
      }
    }
#pragma unroll
    for (int r=0;r<4;r++){
      long row = (long)tile*16 + lg*4 + r;
#pragma unroll
      for (int nt=0;nt<8;nt++){
        int col = nt*16 + lr;
        float v = acc[nt][r] + nb2v[nt] + xf[row*128+col];
        acc[nt][r] = v;
        if (!LN){ xf[row*128+col] = v; xb[row*128+col] = f2b(v); }
      }
    }
    if (LN){
      float s[4] = {0,0,0,0}, q[4] = {0,0,0,0};
#pragma unroll
      for (int r=0;r<4;r++){
#pragma unroll
        for (int nt=0;nt<8;nt++){ float v = acc[nt][r]; s[r] += v; q[r] += v*v; }
      }
#pragma unroll
      for (int mask=1; mask<16; mask<<=1){
#pragma unroll
        for (int r=0;r<4;r++){ s[r] += __shfl_xor(s[r], mask); q[r] += __shfl_xor(q[r], mask); }
      }
#pragma unroll
      for (int r=0;r<4;r++){
        long row = (long)tile*16 + lg*4 + r;
        float mu = s[r]*(1.f/128.f);
        float var = q[r]*(1.f/128.f) - mu*mu;
        float inv = rsqrtf(var + 1e-5f);
#pragma unroll
        for (int nt=0;nt<8;nt++){
          int col = nt*16 + lr;
          float y = (acc[nt][r]-mu)*inv*gv[nt] + bvv[nt];
          if (isbf) ((u16*)outp)[row*128+col] = f2b(y);
          else      ((float*)outp)[row*128+col] = y;
        }
      }
    }
  }
}

// ---------- CSR aggregation: 16 lanes/edge, 4 edges/wave, one wave/node ----------
__global__ __launch_bounds__(256) void agg_kernel(
    const int* __restrict__ rowptr, const int* __restrict__ permsrc,
    const float* __restrict__ pf_in,
    const u16* __restrict__ A, const u16* __restrict__ B,
    const void* __restrict__ ew1, long w1c_off,
    const float* __restrict__ w2p, const float* __restrict__ c2pl,
    const float* __restrict__ pp,
    u16* __restrict__ Hb, float* __restrict__ pf_out, int N,
    const int* __restrict__ flagp)
{
  const int isbf = *flagp;
  int tid = threadIdx.x, lane = tid & 63;
  int t = blockIdx.x*4 + (tid>>6);
  if (t >= N) return;
  int tu = __builtin_amdgcn_readfirstlane(t);   // wave-uniform -> scalar loads
  const int lr = lane & 15, grp = lane >> 4;
  // this lane owns channels [lr*8, lr*8+8) of edge (chunk_base + grp)
  float cch[8], wpv[8], bvv[8];
#pragma unroll
  for (int j=0;j<8;j++){
    cch[j] = ldf(ew1, w1c_off + lr*8 + j, isbf);
    wpv[j] = w2p[lr*8 + j];
  }
  ld8bf(B + (long)tu*128 + lr*8, bvv);
  float c2 = c2pl[0];
  float p0 = pp[0], p1 = pp[1], p2 = pp[2], p3 = pp[3];
  int jb = rowptr[tu], je = rowptr[tu+1];
  float2 pt = *(const float2*)(pf_in + 2*(long)tu);
  float ha[8];
#pragma unroll
  for (int j=0;j<8;j++) ha[j] = 0.f;
  float dpx = 0.f, dpy = 0.f;
  for (int j0 = jb; j0 < je; j0 += 4){
    int e = j0 + grp;
    int ok = e < je;
    int s = permsrc[ok ? e : jb];
    float2 ps = *(const float2*)(pf_in + 2*(long)s);
    float a8[8];
    ld8bf(A + (long)s*128 + lr*8, a8);
    float dx = pt.x - ps.x, dy = pt.y - ps.y;
    float dd = __builtin_amdgcn_sqrtf(dx*dx + dy*dy);
    float okf = ok ? 1.f : 0.f;
    float part = 0.f;
#pragma unroll
    for (int j=0;j<8;j++){
      float h = siluf(a8[j] + bvv[j] + dd*cch[j]) * okf;
      ha[j] += h;
      part += h*wpv[j];
    }
    // 4-step butterfly within the 16-lane group (xor masks stay in-group)
#pragma unroll
    for (int m=1; m<16; m<<=1) part += __shfl_xor(part, m);
    float spre = part + c2 + dd*p0 + p1;
    float pwv  = siluf(spre)*p2 + p3;
    float inv  = __builtin_amdgcn_rcpf(dd + 1e-6f);
    dpx += dx*inv*pwv*okf; dpy += dy*inv*pwv*okf;
  }
  // combine the 4 groups (lanes lr, lr+16, lr+32, lr+48 hold same channels)
#pragma unroll
  for (int j=0;j<8;j++){
    ha[j] += __shfl_xor(ha[j], 16);
    ha[j] += __shfl_xor(ha[j], 32);
  }
  dpx += __shfl_xor(dpx, 16); dpx += __shfl_xor(dpx, 32);
  dpy += __shfl_xor(dpy, 16); dpy += __shfl_xor(dpy, 32);
  if (grp == 0){
    unsigned ov[4];
#pragma unroll
    for (int k=0;k<4;k++) ov[k] = (unsigned)f2b(ha[2*k]) | ((unsigned)f2b(ha[2*k+1])<<16);
    __builtin_memcpy(Hb + (long)tu*128 + lr*8, ov, 16);
  }
  if (lane == 0){
    float2 o; o.x = pt.x + dpx; o.y = pt.y + dpy;
    *(float2*)(pf_out + 2*(long)tu) = o;
  }
}

extern "C" void kernel_launch(void* const* d_in, const int* in_sizes, int n_in,
                              void* d_out, int out_size, void* d_ws, size_t ws_size,
                              hipStream_t stream)
{
  const void* nf  = d_in[0];
  const void* pos = d_in[1];
  const void* npw = d_in[3];
  const void* npb = d_in[4];
  const void* ew1 = d_in[7];
  const void* eb1 = d_in[8];
  const void* ew2 = d_in[9];
  const void* eb2 = d_in[10];
  const void* nw1 = d_in[11];
  const void* nb1 = d_in[12];
  const void* nw2 = d_in[13];
  const void* nb2 = d_in[14];
  const void* pw1 = d_in[15];
  const void* pb1 = d_in[16];
  const void* pw2 = d_in[17];
  const void* pb2 = d_in[18];
  const void* lng = d_in[19];
  const void* lnb = d_in[20];
  const int* eidx = (const int*)d_in[21];
  const int N = NNODES, E = NEDGES;
  const int* srcp = eidx;
  const int* tgtp = eidx + E;

  char* w = (char*)d_ws;
  size_t off = 0;
  auto alloc = [&](size_t bytes)->char* { char* p = w + off; off += (bytes + 255)/256*256; return p; };
  float* xf    = (float*)alloc((size_t)N*128*4);
  u16*   xb    = (u16*)  alloc((size_t)N*128*2);
  u16*   Ab    = (u16*)  alloc((size_t)N*128*2);
  u16*   Bb    = (u16*)  alloc((size_t)N*128*2);
  u16*   Hb    = (u16*)  alloc((size_t)N*128*2);
  float* pf0   = (float*)alloc((size_t)N*2*4);
  float* pf1   = (float*)alloc((size_t)N*2*4);
  int*   cnt   = (int*)  alloc((size_t)N*4);
  int*   rowptr= (int*)  alloc((size_t)(N+1)*4);
  int*   cursor= (int*)  alloc((size_t)N*4);
  float* degf  = (float*)alloc((size_t)N*4);
  int*   perm  = (int*)  alloc((size_t)E*4);
  int*   bsum  = (int*)  alloc(256*4);
  u16*   pk    = (u16*)  alloc((size_t)28*16384*2);
  float* W12f  = (float*)alloc((size_t)4*16384*4);
  float* ebW   = (float*)alloc(4*128*4);
  float* w2p   = (float*)alloc(4*128*4);
  float* c2p   = (float*)alloc(4*4);
  float* pparm = (float*)alloc(16*4);
  int*   flag  = (int*)  alloc(4);
  u16* hb = Ab;   // Ab dead after agg_kernel; rewritten by next mm_ab

  const int NB = (N + 255)/256;  // 196 <= 256
  detect_kernel<<<1, 64, 0, stream>>>(lng, flag);
  hipMemsetAsync(cnt, 0, (size_t)N*4, stream);
  hist_kernel<<<(E+255)/256, 256, 0, stream>>>(tgtp, cnt, E);
  bsum_kernel<<<NB, 256, 0, stream>>>(cnt, bsum, N);
  bscan_kernel<<<1, 256, 0, stream>>>(bsum, NB);
  csr_kernel<<<NB, 256, 0, stream>>>(cnt, bsum, rowptr, cursor, degf, N);
  scatter_kernel<<<(E+255)/256, 256, 0, stream>>>(srcp, tgtp, cursor, perm, E);
  pack_kernel<<<192, 256, 0, stream>>>(ew1, ew2, nw1, nw2, pk, flag);
  w12_kernel<<<512, 128, 0, stream>>>(ew2, nw1, W12f, flag);
  ebw_kernel<<<4, 128, 0, stream>>>(eb2, nw1, ebW, flag);
  pack2_kernel<<<32, 256, 0, stream>>>(W12f, pk);
  w2p_kernel<<<4, 128, 0, stream>>>(ew2, eb2, pw1, w2p, c2p, flag);
  pparm_kernel<<<1, 64, 0, stream>>>(pw1, pb1, pw2, pb2, pparm, flag);
  proj_kernel<<<(N+1)/2, 256, 0, stream>>>(nf, npw, npb, xf, xb, N, flag);
  cvtp_kernel<<<(2*N+255)/256, 256, 0, stream>>>(pos, pf0, 2*N, flag);

  // layer 0 A/B from projected x
  mm_ab_kernel<<<MMGRID, 256, 65536, stream>>>(xb, pk + 0*16384, pk + 1*16384,
                                               eb1, 0, Ab, Bb, flag);
  for (int l = 0; l < 4; l++){
    const u16* NW1a = pk + (l*6+3)*16384;
    const u16* NW2p = pk + (l*6+5)*16384;
    const u16* W12p = pk + (24+l)*16384;
    float* pin  = (l & 1) ? pf1 : pf0;
    float* pout = (l & 1) ? pf0 : pf1;

    agg_kernel<<<(N+3)/4, 256, 0, stream>>>(
        rowptr, perm, pin, Ab, Bb,
        ew1, (long)l*257*128 + 256*128,
        w2p + l*128, c2p + l, pparm + l*4,
        Hb, pout, N, flag);
    mm_hidden_kernel<<<MMGRID, 256, 65536, stream>>>(
        xb, Hb, NW1a, W12p, nb1, (long)l*128, degf, ebW + l*128, hb, flag);
    if (l < 3){
      mm_res_kernel<0><<<MMGRID, 256, 32768, stream>>>(
          hb, NW2p, nb2, (long)l*128, xf, xb, nullptr, nullptr, nullptr, flag);
      mm_ab_kernel<<<MMGRID, 256, 65536, stream>>>(
          xb, pk + ((l+1)*6+0)*16384, pk + ((l+1)*6+1)*16384,
          eb1, (long)(l+1)*128, Ab, Bb, flag);
    } else {
      mm_res_kernel<1><<<MMGRID, 256, 32768, stream>>>(
          hb, NW2p, nb2, (long)l*128, xf, nullptr, lng, lnb, d_out, flag);
    }
  }
}

// Round 9
// 782.112 us; speedup vs baseline: 1.0832x; 1.0832x over previous
//
#include <hip/hip_runtime.h>
#include <hip/hip_bf16.h>

// EGNN encoder, N=50000, E=250000, D=128, L=4. bf16 inputs/output (verified R2).
// R3: CSR-by-tgt aggregation (no atomics), EW2@NW1b folding.
// R4: 3-stage parallel CSR scan.  R5: agg chunked x4 + fast rcp.
// R6: mega-fusion REGRESSED -> reverted.
// R7: weight-stationary streaming matmuls (LDS-staged weights, grid-stride).
// R8: transposed agg REGRESSED (killed memory-level parallelism) -> reverted.
// R9: R5-shape agg with 8-edge batches (16 loads in flight; Poisson(5) degree
//     -> ~92% of nodes finish in one latency round).

#define NNODES 50000
#define NEDGES 250000
#define NTILES 3125   // 50000/16 exactly, no tail
#define MMGRID 512

typedef unsigned short u16;
typedef __attribute__((ext_vector_type(8))) short bf16x8;
typedef __attribute__((ext_vector_type(4))) float floatx4;

__device__ __forceinline__ float b2f(u16 h){ unsigned u=((unsigned)h)<<16; float f; __builtin_memcpy(&f,&u,4); return f; }
__device__ __forceinline__ u16 f2b(float f){ unsigned u; __builtin_memcpy(&u,&f,4); u = u + 0x7FFFu + ((u>>16)&1u); return (u16)(u>>16); }
__device__ __forceinline__ float siluf(float x){ return x*__builtin_amdgcn_rcpf(1.f+__expf(-x)); }
__device__ __forceinline__ float ldf(const void* p, long i, int isbf){
  return isbf ? b2f(((const u16*)p)[i]) : ((const float*)p)[i];
}

__global__ void detect_kernel(const void* lng, int* flag){
  if (threadIdx.x==0 && blockIdx.x==0) *flag = (((const u16*)lng)[0] != 0) ? 1 : 0;
}

// ---------- weight packing into MFMA B-fragment order (24 input matrices) ----------
__global__ __launch_bounds__(256) void pack_kernel(
    const void* __restrict__ ew1, const void* __restrict__ ew2,
    const void* __restrict__ nw1, const void* __restrict__ nw2,
    u16* __restrict__ packed, const int* __restrict__ flagp)
{
  const int isbf = *flagp;
  int t = blockIdx.x*256 + threadIdx.x;       // 24 * 2048
  int m = t >> 11; int r = t & 2047;
  int lane = r & 63; int ntk = r >> 6;
  int kk = ntk >> 3, nt = ntk & 7;
  int l = m/6, w = m%6;
  const void* src; long off;
  switch(w){
    case 0: src=ew1; off=(long)l*257*128;            break; // W1a
    case 1: src=ew1; off=(long)l*257*128 + 128*128;  break; // W1b
    case 2: src=ew2; off=(long)l*128*128;            break; // EW2
    case 3: src=nw1; off=(long)l*256*128;            break; // NW1a
    case 4: src=nw1; off=(long)l*256*128 + 128*128;  break; // NW1b
    default:src=nw2; off=(long)l*128*128;            break; // NW2
  }
  int c  = nt*16 + (lane & 15);
  int k0 = kk*32 + (lane >> 4)*8;
  u16 vals[8];
#pragma unroll
  for (int j=0;j<8;j++){
    long idx = off + (long)(k0+j)*128 + c;
    vals[j] = isbf ? ((const u16*)src)[idx] : f2b(((const float*)src)[idx]);
  }
  bf16x8 v; __builtin_memcpy(&v, vals, 16);
  *(bf16x8*)(packed + (long)t*8) = v;
}

// ---------- pack fp32 W12[l] (4 matrices) into chunks 24..27 ----------
__global__ __launch_bounds__(256) void pack2_kernel(
    const float* __restrict__ W12f, u16* __restrict__ packed)
{
  int t = blockIdx.x*256 + threadIdx.x;       // 4 * 2048
  int m = t >> 11; int r = t & 2047;
  int lane = r & 63; int ntk = r >> 6;
  int kk = ntk >> 3, nt = ntk & 7;
  const float* base = W12f + (long)m*16384;
  int c  = nt*16 + (lane & 15);
  int k0 = kk*32 + (lane >> 4)*8;
  u16 vals[8];
#pragma unroll
  for (int j=0;j<8;j++) vals[j] = f2b(base[(long)(k0+j)*128 + c]);
  bf16x8 v; __builtin_memcpy(&v, vals, 16);
  *(bf16x8*)(packed + ((long)(24+m)*2048 + r)*8) = v;
}

// ---------- W12[l][k][j] = sum_d EW2[l][k][d]*NW1b[l][d][j] (fp32) ----------
__global__ __launch_bounds__(128) void w12_kernel(
    const void* __restrict__ ew2, const void* __restrict__ nw1,
    float* __restrict__ W12f, const int* __restrict__ flagp)
{
  const int isbf = *flagp;
  int l = blockIdx.x >> 7, k = blockIdx.x & 127, j = threadIdx.x;
  long e2 = (long)l*16384 + (long)k*128;
  long nb = (long)l*256*128 + 128*128;
  float acc = 0.f;
  for (int d=0; d<128; d++)
    acc += ldf(ew2, e2 + d, isbf) * ldf(nw1, nb + (long)d*128 + j, isbf);
  W12f[(long)l*16384 + (long)k*128 + j] = acc;
}

// ---------- ebW[l][j] = sum_d eb2[l][d]*NW1b[l][d][j] ----------
__global__ __launch_bounds__(128) void ebw_kernel(
    const void* __restrict__ eb2, const void* __restrict__ nw1,
    float* __restrict__ ebW, const int* __restrict__ flagp)
{
  const int isbf = *flagp;
  int l = blockIdx.x, j = threadIdx.x;
  long nb = (long)l*256*128 + 128*128;
  float acc = 0.f;
  for (int d=0; d<128; d++)
    acc += ldf(eb2, (long)l*128 + d, isbf) * ldf(nw1, nb + (long)d*128 + j, isbf);
  ebW[l*128+j] = acc;
}

// ---------- per-layer w2p = EW2 @ pw1[0:128], c2p = eb2 . pw1[0:128] ----------
__global__ __launch_bounds__(128) void w2p_kernel(
    const void* __restrict__ ew2, const void* __restrict__ eb2, const void* __restrict__ pw1,
    float* __restrict__ w2p, float* __restrict__ c2p, const int* __restrict__ flagp)
{
  const int isbf = *flagp;
  int l = blockIdx.x, i = threadIdx.x;
  long Woff = (long)l*128*128, poff = (long)l*129;
  float acc = 0.f;
  for (int j=0;j<128;j++) acc += ldf(ew2, Woff + (long)i*128 + j, isbf) * ldf(pw1, poff + j, isbf);
  w2p[l*128+i] = acc;
  __shared__ float red[128];
  red[i] = ldf(eb2, (long)l*128 + i, isbf) * ldf(pw1, poff + i, isbf);
  __syncthreads();
  for (int st=64; st>0; st>>=1){ if (i<st) red[i]+=red[i+st]; __syncthreads(); }
  if (i==0) c2p[l] = red[0];
}

__global__ void pparm_kernel(const void* pw1, const void* pb1, const void* pw2, const void* pb2,
                             float* pparm, const int* flagp)
{
  const int isbf = *flagp;
  int l = threadIdx.x;
  if (l < 4){
    pparm[l*4+0] = ldf(pw1, (long)l*129 + 128, isbf);
    pparm[l*4+1] = ldf(pb1, l, isbf);
    pparm[l*4+2] = ldf(pw2, l, isbf);
    pparm[l*4+3] = ldf(pb2, l, isbf);
  }
}

// ---------- CSR build: histogram, 3-stage scan, scatter ----------
__global__ __launch_bounds__(256) void hist_kernel(const int* __restrict__ tgt, int* __restrict__ cnt, int E){
  int i = blockIdx.x*256 + threadIdx.x;
  if (i < E) atomicAdd(&cnt[tgt[i]], 1);
}

__global__ __launch_bounds__(256) void bsum_kernel(const int* __restrict__ cnt, int* __restrict__ bsum, int N){
  int i = blockIdx.x*256 + threadIdx.x;
  int v = (i < N) ? cnt[i] : 0;
#pragma unroll
  for (int off=32; off; off>>=1) v += __shfl_down(v, off);
  __shared__ int ws[4];
  if ((threadIdx.x & 63) == 0) ws[threadIdx.x>>6] = v;
  __syncthreads();
  if (threadIdx.x == 0) bsum[blockIdx.x] = ws[0]+ws[1]+ws[2]+ws[3];
}

__global__ __launch_bounds__(256) void bscan_kernel(int* __restrict__ bsum, int nb){
  __shared__ int lds[256];
  int i = threadIdx.x;
  int v = (i < nb) ? bsum[i] : 0;
  lds[i] = v; __syncthreads();
#pragma unroll
  for (int off=1; off<256; off<<=1){
    int t = (i>=off)? lds[i-off] : 0; __syncthreads();
    lds[i] += t; __syncthreads();
  }
  if (i < nb) bsum[i] = lds[i] - v;  // exclusive prefix
}

__global__ __launch_bounds__(256) void csr_kernel(
    const int* __restrict__ cnt, const int* __restrict__ bsum,
    int* __restrict__ rowptr, int* __restrict__ cursor, float* __restrict__ degf, int N)
{
  __shared__ int lds[256];
  int i = blockIdx.x*256 + threadIdx.x;
  int c = (i < N) ? cnt[i] : 0;
  lds[threadIdx.x] = c; __syncthreads();
#pragma unroll
  for (int off=1; off<256; off<<=1){
    int t = (threadIdx.x>=off)? lds[threadIdx.x-off] : 0; __syncthreads();
    lds[threadIdx.x] += t; __syncthreads();
  }
  int run = bsum[blockIdx.x] + lds[threadIdx.x] - c;  // exclusive
  if (i < N){
    rowptr[i] = run; cursor[i] = run; degf[i] = (float)c;
    if (i == N-1) rowptr[N] = run + c;
  }
}

__global__ __launch_bounds__(256) void scatter_kernel(
    const int* __restrict__ src, const int* __restrict__ tgt,
    int* __restrict__ cursor, int* __restrict__ permsrc, int E)
{
  int e = blockIdx.x*256 + threadIdx.x;
  if (e >= E) return;
  int t = tgt[e];
  int p = atomicAdd(&cursor[t], 1);
  permsrc[p] = src[e];
}

// ---------- initial projection x = nf @ npw + npb (2 nodes/block) ----------
__global__ __launch_bounds__(256) void proj_kernel(
    const void* __restrict__ nf, const void* __restrict__ W, const void* __restrict__ bvec,
    float* __restrict__ xf, u16* __restrict__ xb, int N, const int* __restrict__ flagp)
{
  const int isbf = *flagp;
  int n = blockIdx.x*2 + (threadIdx.x>>7), d = threadIdx.x & 127;
  if (n >= N) return;
  float acc = ldf(bvec, d, isbf);
#pragma unroll
  for (int f=0; f<12; f++) acc += ldf(nf, (long)n*12+f, isbf) * ldf(W, f*128+d, isbf);
  xf[(long)n*128+d] = acc;
  xb[(long)n*128+d] = f2b(acc);
}

__global__ __launch_bounds__(256) void cvtp_kernel(const void* __restrict__ pos, float* __restrict__ pf,
                                                   int n, const int* __restrict__ flagp){
  const int isbf = *flagp;
  int i = blockIdx.x*256 + threadIdx.x;
  if (i < n) pf[i] = ldf(pos, i, isbf);
}

// ---------- streaming A/B matmul: Ab = bf16(x@Wa+eb1), Bb = bf16(x@Wb) ----------
__global__ __launch_bounds__(256) void mm_ab_kernel(
    const u16* __restrict__ X, const u16* __restrict__ Wa, const u16* __restrict__ Wb,
    const void* __restrict__ bias, long bias_off,
    u16* __restrict__ Ab, u16* __restrict__ Bb, const int* __restrict__ flagp)
{
  extern __shared__ u16 wlds[];
  const int tid = threadIdx.x, wave = tid>>6, lane = tid&63;
  const int isbf = *flagp;
  const int lr = lane&15, lg = lane>>4;
  for (int i=tid; i<2048; i+=256){
    *(bf16x8*)(wlds + (long)i*8)          = *(const bf16x8*)(Wa + (long)i*8);
    *(bf16x8*)(wlds + 16384 + (long)i*8)  = *(const bf16x8*)(Wb + (long)i*8);
  }
  float biasv[8];
#pragma unroll
  for (int nt=0;nt<8;nt++) biasv[nt] = ldf(bias, bias_off + nt*16 + lr, isbf);
  __syncthreads();
  for (int tile = blockIdx.x*4 + wave; tile < NTILES; tile += MMGRID*4){
    const u16* xr = X + ((long)tile*16 + lr)*128;
    bf16x8 a[4];
#pragma unroll
    for (int kk=0;kk<4;kk++) a[kk] = *(const bf16x8*)(xr + kk*32 + lg*8);
    floatx4 accA[8], accB[8];
#pragma unroll
    for (int i=0;i<8;i++){ accA[i]=(floatx4){0,0,0,0}; accB[i]=(floatx4){0,0,0,0}; }
#pragma unroll
    for (int kk=0;kk<4;kk++){
#pragma unroll
      for (int nt=0;nt<8;nt++){
        bf16x8 ba = *(const bf16x8*)(wlds + ((kk*8+nt)*64 + lane)*8);
        accA[nt] = __builtin_amdgcn_mfma_f32_16x16x32_bf16(a[kk], ba, accA[nt], 0, 0, 0);
        bf16x8 bb = *(const bf16x8*)(wlds + 16384 + ((kk*8+nt)*64 + lane)*8);
        accB[nt] = __builtin_amdgcn_mfma_f32_16x16x32_bf16(a[kk], bb, accB[nt], 0, 0, 0);
      }
    }
#pragma unroll
    for (int r=0;r<4;r++){
      long row = (long)tile*16 + lg*4 + r;
#pragma unroll
      for (int nt=0;nt<8;nt++){
        int col = nt*16 + lr;
        Ab[row*128+col] = f2b(accA[nt][r] + biasv[nt]);
        Bb[row*128+col] = f2b(accB[nt][r]);
      }
    }
  }
}

// ---------- streaming hidden matmul: hb = bf16(silu(xb@NW1a + Hb@W12 + deg*ebW + nb1)) ----------
__global__ __launch_bounds__(256) void mm_hidden_kernel(
    const u16* __restrict__ X, const u16* __restrict__ H,
    const u16* __restrict__ W1, const u16* __restrict__ W2,
    const void* __restrict__ nb1, long nb1_off,
    const float* __restrict__ degf, const float* __restrict__ ebW,
    u16* __restrict__ hb, const int* __restrict__ flagp)
{
  extern __shared__ u16 wlds[];
  const int tid = threadIdx.x, wave = tid>>6, lane = tid&63;
  const int isbf = *flagp;
  const int lr = lane&15, lg = lane>>4;
  for (int i=tid; i<2048; i+=256){
    *(bf16x8*)(wlds + (long)i*8)          = *(const bf16x8*)(W1 + (long)i*8);
    *(bf16x8*)(wlds + 16384 + (long)i*8)  = *(const bf16x8*)(W2 + (long)i*8);
  }
  float nb1v[8], ebv[8];
#pragma unroll
  for (int nt=0;nt<8;nt++){ int col=nt*16+lr; nb1v[nt]=ldf(nb1, nb1_off+col, isbf); ebv[nt]=ebW[col]; }
  __syncthreads();
  for (int tile = blockIdx.x*4 + wave; tile < NTILES; tile += MMGRID*4){
    const u16* xr = X + ((long)tile*16 + lr)*128;
    const u16* hr = H + ((long)tile*16 + lr)*128;
    bf16x8 ax[4], ah[4];
#pragma unroll
    for (int kk=0;kk<4;kk++){
      ax[kk] = *(const bf16x8*)(xr + kk*32 + lg*8);
      ah[kk] = *(const bf16x8*)(hr + kk*32 + lg*8);
    }
    floatx4 acc[8];
#pragma unroll
    for (int i=0;i<8;i++) acc[i]=(floatx4){0,0,0,0};
#pragma unroll
    for (int kk=0;kk<4;kk++){
#pragma unroll
      for (int nt=0;nt<8;nt++){
        bf16x8 b1 = *(const bf16x8*)(wlds + ((kk*8+nt)*64 + lane)*8);
        acc[nt] = __builtin_amdgcn_mfma_f32_16x16x32_bf16(ax[kk], b1, acc[nt], 0, 0, 0);
        bf16x8 b2 = *(const bf16x8*)(wlds + 16384 + ((kk*8+nt)*64 + lane)*8);
        acc[nt] = __builtin_amdgcn_mfma_f32_16x16x32_bf16(ah[kk], b2, acc[nt], 0, 0, 0);
      }
    }
    float dv[4];
#pragma unroll
    for (int r=0;r<4;r++) dv[r] = degf[(long)tile*16 + lg*4 + r];
#pragma unroll
    for (int r=0;r<4;r++){
      long row = (long)tile*16 + lg*4 + r;
#pragma unroll
      for (int nt=0;nt<8;nt++){
        int col = nt*16 + lr;
        hb[row*128+col] = f2b(siluf(acc[nt][r] + nb1v[nt] + dv[r]*ebv[nt]));
      }
    }
  }
}

// ---------- streaming residual matmul: xnew = xf + hb@NW2 + nb2 ----------
template<int LN>
__global__ __launch_bounds__(256) void mm_res_kernel(
    const u16* __restrict__ H, const u16* __restrict__ W,
    const void* __restrict__ nb2, long nb2_off,
    float* __restrict__ xf, u16* __restrict__ xb,
    const void* __restrict__ lng, const void* __restrict__ lnb, void* __restrict__ outp,
    const int* __restrict__ flagp)
{
  extern __shared__ u16 wlds[];
  const int tid = threadIdx.x, wave = tid>>6, lane = tid&63;
  const int isbf = *flagp;
  const int lr = lane&15, lg = lane>>4;
  for (int i=tid; i<2048; i+=256)
    *(bf16x8*)(wlds + (long)i*8) = *(const bf16x8*)(W + (long)i*8);
  float nb2v[8];
#pragma unroll
  for (int nt=0;nt<8;nt++) nb2v[nt] = ldf(nb2, nb2_off + nt*16 + lr, isbf);
  float gv[8], bvv[8];
  if (LN){
#pragma unroll
    for (int nt=0;nt<8;nt++){ int col=nt*16+lr; gv[nt]=ldf(lng,col,isbf); bvv[nt]=ldf(lnb,col,isbf); }
  }
  __syncthreads();
  for (int tile = blockIdx.x*4 + wave; tile < NTILES; tile += MMGRID*4){
    const u16* hr = H + ((long)tile*16 + lr)*128;
    bf16x8 a[4];
#pragma unroll
    for (int kk=0;kk<4;kk++) a[kk] = *(const bf16x8*)(hr + kk*32 + lg*8);
    floatx4 acc[8];
#pragma unroll
    for (int i=0;i<8;i++) acc[i]=(floatx4){0,0,0,0};
#pragma unroll
    for (int kk=0;kk<4;kk++){
#pragma unroll
      for (int nt=0;nt<8;nt++){
        bf16x8 b = *(const bf16x8*)(wlds + ((kk*8+nt)*64 + lane)*8);
        acc[nt] = __builtin_amdgcn_mfma_f32_16x16x32_bf16(a[kk], b, acc[nt], 0, 0, 0);
      }
    }
#pragma unroll
    for (int r=0;r<4;r++){
      long row = (long)tile*16 + lg*4 + r;
#pragma unroll
      for (int nt=0;nt<8;nt++){
        int col = nt*16 + lr;
        float v = acc[nt][r] + nb2v[nt] + xf[row*128+col];
        acc[nt][r] = v;
        if (!LN){ xf[row*128+col] = v; xb[row*128+col] = f2b(v); }
      }
    }
    if (LN){
      float s[4] = {0,0,0,0}, q[4] = {0,0,0,0};
#pragma unroll
      for (int r=0;r<4;r++){
#pragma unroll
        for (int nt=0;nt<8;nt++){ float v = acc[nt][r]; s[r] += v; q[r] += v*v; }
      }
#pragma unroll
      for (int mask=1; mask<16; mask<<=1){
#pragma unroll
        for (int r=0;r<4;r++){ s[r] += __shfl_xor(s[r], mask); q[r] += __shfl_xor(q[r], mask); }
      }
#pragma unroll
      for (int r=0;r<4;r++){
        long row = (long)tile*16 + lg*4 + r;
        float mu = s[r]*(1.f/128.f);
        float var = q[r]*(1.f/128.f) - mu*mu;
        float inv = rsqrtf(var + 1e-5f);
#pragma unroll
        for (int nt=0;nt<8;nt++){
          int col = nt*16 + lr;
          float y = (acc[nt][r]-mu)*inv*gv[nt] + bvv[nt];
          if (isbf) ((u16*)outp)[row*128+col] = f2b(y);
          else      ((float*)outp)[row*128+col] = y;
        }
      }
    }
  }
}

// ---------- CSR aggregation: one wave per target node, 8-edge batches ----------
__global__ __launch_bounds__(256) void agg_kernel(
    const int* __restrict__ rowptr, const int* __restrict__ permsrc,
    const float* __restrict__ pf_in,
    const u16* __restrict__ A, const u16* __restrict__ B,
    const void* __restrict__ ew1, long w1c_off,
    const float* __restrict__ w2p, const float* __restrict__ c2pl,
    const float* __restrict__ pp,
    u16* __restrict__ Hb, float* __restrict__ pf_out, int N,
    const int* __restrict__ flagp)
{
  const int isbf = *flagp;
  int tid = threadIdx.x, lane = tid & 63;
  int t = blockIdx.x*4 + (tid>>6);
  if (t >= N) return;
  int tu = __builtin_amdgcn_readfirstlane(t);   // wave-uniform -> scalar loads
  float c0 = ldf(ew1, w1c_off + 2*lane,     isbf);
  float c1 = ldf(ew1, w1c_off + 2*lane + 1, isbf);
  float2 wp = *(const float2*)(w2p + 2*lane);
  float c2 = c2pl[0];
  float p0 = pp[0], p1 = pp[1], p2 = pp[2], p3 = pp[3];
  int jb = rowptr[tu], je = rowptr[tu+1];
  float2 pt = *(const float2*)(pf_in + 2*(long)tu);
  unsigned bv = *(const unsigned*)(B + (long)tu*128 + 2*lane);
  float b0 = b2f((u16)bv), b1 = b2f((u16)(bv>>16));
  float h0a = 0.f, h1a = 0.f, dpx = 0.f, dpy = 0.f;
  for (int j0 = jb; j0 < je; j0 += 8){
    int m = je - j0; if (m > 8) m = 8;
    int s[8]; float2 ps[8]; unsigned av[8];
    float part[8], dist[8], dxv[8], dyv[8];
    // batched index loads (scalar: j0+c uniform)
#pragma unroll
    for (int c=0;c<8;c++) if (c<m) s[c] = permsrc[j0+c];
    // batched data loads — up to 16 independent loads in flight
#pragma unroll
    for (int c=0;c<8;c++) if (c<m){
      ps[c] = *(const float2*)(pf_in + 2*(long)s[c]);
      av[c] = *(const unsigned*)(A + (long)s[c]*128 + 2*lane);
    }
    // per-edge h / partial dot (ILP across batch)
#pragma unroll
    for (int c=0;c<8;c++){
      if (c<m){
        float dx = pt.x - ps[c].x, dy = pt.y - ps[c].y;
        float d2 = dx*dx + dy*dy;
        float dd = __builtin_amdgcn_sqrtf(d2);
        float h0 = siluf(b2f((u16)av[c])       + b0 + dd*c0);
        float h1 = siluf(b2f((u16)(av[c]>>16)) + b1 + dd*c1);
        h0a += h0; h1a += h1;
        part[c] = h0*wp.x + h1*wp.y;
        dist[c] = dd; dxv[c] = dx; dyv[c] = dy;
      } else part[c] = 0.f;
    }
    // interleaved butterflies: 8 independent 6-step chains overlap
#pragma unroll
    for (int off=32; off; off>>=1){
#pragma unroll
      for (int c=0;c<8;c++) part[c] += __shfl_xor(part[c], off);
    }
    // per-edge scalar MLP + pos accumulation (ILP across batch)
#pragma unroll
    for (int c=0;c<8;c++){
      if (c<m){
        float spre = part[c] + c2 + dist[c]*p0 + p1;
        float pwv  = siluf(spre)*p2 + p3;
        float inv  = __builtin_amdgcn_rcpf(dist[c] + 1e-6f);
        dpx += dxv[c]*inv*pwv; dpy += dyv[c]*inv*pwv;
      }
    }
  }
  *(unsigned*)(Hb + (long)tu*128 + 2*lane) = (unsigned)f2b(h0a) | ((unsigned)f2b(h1a)<<16);
  if (lane == 0){
    float2 o; o.x = pt.x + dpx; o.y = pt.y + dpy;
    *(float2*)(pf_out + 2*(long)tu) = o;
  }
}

extern "C" void kernel_launch(void* const* d_in, const int* in_sizes, int n_in,
                              void* d_out, int out_size, void* d_ws, size_t ws_size,
                              hipStream_t stream)
{
  const void* nf  = d_in[0];
  const void* pos = d_in[1];
  const void* npw = d_in[3];
  const void* npb = d_in[4];
  const void* ew1 = d_in[7];
  const void* eb1 = d_in[8];
  const void* ew2 = d_in[9];
  const void* eb2 = d_in[10];
  const void* nw1 = d_in[11];
  const void* nb1 = d_in[12];
  const void* nw2 = d_in[13];
  const void* nb2 = d_in[14];
  const void* pw1 = d_in[15];
  const void* pb1 = d_in[16];
  const void* pw2 = d_in[17];
  const void* pb2 = d_in[18];
  const void* lng = d_in[19];
  const void* lnb = d_in[20];
  const int* eidx = (const int*)d_in[21];
  const int N = NNODES, E = NEDGES;
  const int* srcp = eidx;
  const int* tgtp = eidx + E;

  char* w = (char*)d_ws;
  size_t off = 0;
  auto alloc = [&](size_t bytes)->char* { char* p = w + off; off += (bytes + 255)/256*256; return p; };
  float* xf    = (float*)alloc((size_t)N*128*4);
  u16*   xb    = (u16*)  alloc((size_t)N*128*2);
  u16*   Ab    = (u16*)  alloc((size_t)N*128*2);
  u16*   Bb    = (u16*)  alloc((size_t)N*128*2);
  u16*   Hb    = (u16*)  alloc((size_t)N*128*2);
  float* pf0   = (float*)alloc((size_t)N*2*4);
  float* pf1   = (float*)alloc((size_t)N*2*4);
  int*   cnt   = (int*)  alloc((size_t)N*4);
  int*   rowptr= (int*)  alloc((size_t)(N+1)*4);
  int*   cursor= (int*)  alloc((size_t)N*4);
  float* degf  = (float*)alloc((size_t)N*4);
  int*   perm  = (int*)  alloc((size_t)E*4);
  int*   bsum  = (int*)  alloc(256*4);
  u16*   pk    = (u16*)  alloc((size_t)28*16384*2);
  float* W12f  = (float*)alloc((size_t)4*16384*4);
  float* ebW   = (float*)alloc(4*128*4);
  float* w2p   = (float*)alloc(4*128*4);
  float* c2p   = (float*)alloc(4*4);
  float* pparm = (float*)alloc(16*4);
  int*   flag  = (int*)  alloc(4);
  u16* hb = Ab;   // Ab dead after agg_kernel; rewritten by next mm_ab

  const int NB = (N + 255)/256;  // 196 <= 256
  detect_kernel<<<1, 64, 0, stream>>>(lng, flag);
  hipMemsetAsync(cnt, 0, (size_t)N*4, stream);
  hist_kernel<<<(E+255)/256, 256, 0, stream>>>(tgtp, cnt, E);
  bsum_kernel<<<NB, 256, 0, stream>>>(cnt, bsum, N);
  bscan_kernel<<<1, 256, 0, stream>>>(bsum, NB);
  csr_kernel<<<NB, 256, 0, stream>>>(cnt, bsum, rowptr, cursor, degf, N);
  scatter_kernel<<<(E+255)/256, 256, 0, stream>>>(srcp, tgtp, cursor, perm, E);
  pack_kernel<<<192, 256, 0, stream>>>(ew1, ew2, nw1, nw2, pk, flag);
  w12_kernel<<<512, 128, 0, stream>>>(ew2, nw1, W12f, flag);
  ebw_kernel<<<4, 128, 0, stream>>>(eb2, nw1, ebW, flag);
  pack2_kernel<<<32, 256, 0, stream>>>(W12f, pk);
  w2p_kernel<<<4, 128, 0, stream>>>(ew2, eb2, pw1, w2p, c2p, flag);
  pparm_kernel<<<1, 64, 0, stream>>>(pw1, pb1, pw2, pb2, pparm, flag);
  proj_kernel<<<(N+1)/2, 256, 0, stream>>>(nf, npw, npb, xf, xb, N, flag);
  cvtp_kernel<<<(2*N+255)/256, 256, 0, stream>>>(pos, pf0, 2*N, flag);

  // layer 0 A/B from projected x
  mm_ab_kernel<<<MMGRID, 256, 65536, stream>>>(xb, pk + 0*16384, pk + 1*16384,
                                               eb1, 0, Ab, Bb, flag);
  for (int l = 0; l < 4; l++){
    const u16* NW1a = pk + (l*6+3)*16384;
    const u16* NW2p = pk + (l*6+5)*16384;
    const u16* W12p = pk + (24+l)*16384;
    float* pin  = (l & 1) ? pf1 : pf0;
    float* pout = (l & 1) ? pf0 : pf1;

    agg_kernel<<<(N+3)/4, 256, 0, stream>>>(
        rowptr, perm, pin, Ab, Bb,
        ew1, (long)l*257*128 + 256*128,
        w2p + l*128, c2p + l, pparm + l*4,
        Hb, pout, N, flag);
    mm_hidden_kernel<<<MMGRID, 256, 65536, stream>>>(
        xb, Hb, NW1a, W12p, nb1, (long)l*128, degf, ebW + l*128, hb, flag);
    if (l < 3){
      mm_res_kernel<0><<<MMGRID, 256, 32768, stream>>>(
          hb, NW2p, nb2, (long)l*128, xf, xb, nullptr, nullptr, nullptr, flag);
      mm_ab_kernel<<<MMGRID, 256, 65536, stream>>>(
          xb, pk + ((l+1)*6+0)*16384, pk + ((l+1)*6+1)*16384,
          eb1, (long)(l+1)*128, Ab, Bb, flag);
    } else {
      mm_res_kernel<1><<<MMGRID, 256, 32768, stream>>>(
          hb, NW2p, nb2, (long)l*128, xf, nullptr, lng, lnb, d_out, flag);
    }
  }
}

// Round 10
// 579.553 us; speedup vs baseline: 1.4618x; 1.3495x over previous
//
#include <hip/hip_runtime.h>
#include <hip/hip_bf16.h>

// EGNN encoder, N=50000, E=250000, D=128, L=4. bf16 inputs/output (verified R2).
// R3: CSR-by-tgt aggregation (no atomics), EW2@NW1b folding.
// R4: 3-stage parallel CSR scan.  R5: agg chunked x4 + fast rcp (VGPR 32 — occupancy
//     is the latency-hider; R8/R9 both regressed by killing it).
// R7: weight-stationary streaming matmuls (LDS-staged weights, grid-stride).
// R10: bf16-only residual stream (xf fp32 master removed): mm_res traffic 77->38 MB/layer.

#define NNODES 50000
#define NEDGES 250000
#define NTILES 3125   // 50000/16 exactly, no tail
#define MMGRID 512

typedef unsigned short u16;
typedef __attribute__((ext_vector_type(8))) short bf16x8;
typedef __attribute__((ext_vector_type(4))) float floatx4;

__device__ __forceinline__ float b2f(u16 h){ unsigned u=((unsigned)h)<<16; float f; __builtin_memcpy(&f,&u,4); return f; }
__device__ __forceinline__ u16 f2b(float f){ unsigned u; __builtin_memcpy(&u,&f,4); u = u + 0x7FFFu + ((u>>16)&1u); return (u16)(u>>16); }
__device__ __forceinline__ float siluf(float x){ return x*__builtin_amdgcn_rcpf(1.f+__expf(-x)); }
__device__ __forceinline__ float ldf(const void* p, long i, int isbf){
  return isbf ? b2f(((const u16*)p)[i]) : ((const float*)p)[i];
}

__global__ void detect_kernel(const void* lng, int* flag){
  if (threadIdx.x==0 && blockIdx.x==0) *flag = (((const u16*)lng)[0] != 0) ? 1 : 0;
}

// ---------- weight packing into MFMA B-fragment order (24 input matrices) ----------
__global__ __launch_bounds__(256) void pack_kernel(
    const void* __restrict__ ew1, const void* __restrict__ ew2,
    const void* __restrict__ nw1, const void* __restrict__ nw2,
    u16* __restrict__ packed, const int* __restrict__ flagp)
{
  const int isbf = *flagp;
  int t = blockIdx.x*256 + threadIdx.x;       // 24 * 2048
  int m = t >> 11; int r = t & 2047;
  int lane = r & 63; int ntk = r >> 6;
  int kk = ntk >> 3, nt = ntk & 7;
  int l = m/6, w = m%6;
  const void* src; long off;
  switch(w){
    case 0: src=ew1; off=(long)l*257*128;            break; // W1a
    case 1: src=ew1; off=(long)l*257*128 + 128*128;  break; // W1b
    case 2: src=ew2; off=(long)l*128*128;            break; // EW2
    case 3: src=nw1; off=(long)l*256*128;            break; // NW1a
    case 4: src=nw1; off=(long)l*256*128 + 128*128;  break; // NW1b
    default:src=nw2; off=(long)l*128*128;            break; // NW2
  }
  int c  = nt*16 + (lane & 15);
  int k0 = kk*32 + (lane >> 4)*8;
  u16 vals[8];
#pragma unroll
  for (int j=0;j<8;j++){
    long idx = off + (long)(k0+j)*128 + c;
    vals[j] = isbf ? ((const u16*)src)[idx] : f2b(((const float*)src)[idx]);
  }
  bf16x8 v; __builtin_memcpy(&v, vals, 16);
  *(bf16x8*)(packed + (long)t*8) = v;
}

// ---------- pack fp32 W12[l] (4 matrices) into chunks 24..27 ----------
__global__ __launch_bounds__(256) void pack2_kernel(
    const float* __restrict__ W12f, u16* __restrict__ packed)
{
  int t = blockIdx.x*256 + threadIdx.x;       // 4 * 2048
  int m = t >> 11; int r = t & 2047;
  int lane = r & 63; int ntk = r >> 6;
  int kk = ntk >> 3, nt = ntk & 7;
  const float* base = W12f + (long)m*16384;
  int c  = nt*16 + (lane & 15);
  int k0 = kk*32 + (lane >> 4)*8;
  u16 vals[8];
#pragma unroll
  for (int j=0;j<8;j++) vals[j] = f2b(base[(long)(k0+j)*128 + c]);
  bf16x8 v; __builtin_memcpy(&v, vals, 16);
  *(bf16x8*)(packed + ((long)(24+m)*2048 + r)*8) = v;
}

// ---------- W12[l][k][j] = sum_d EW2[l][k][d]*NW1b[l][d][j] (fp32) ----------
__global__ __launch_bounds__(128) void w12_kernel(
    const void* __restrict__ ew2, const void* __restrict__ nw1,
    float* __restrict__ W12f, const int* __restrict__ flagp)
{
  const int isbf = *flagp;
  int l = blockIdx.x >> 7, k = blockIdx.x & 127, j = threadIdx.x;
  long e2 = (long)l*16384 + (long)k*128;
  long nb = (long)l*256*128 + 128*128;
  float acc = 0.f;
  for (int d=0; d<128; d++)
    acc += ldf(ew2, e2 + d, isbf) * ldf(nw1, nb + (long)d*128 + j, isbf);
  W12f[(long)l*16384 + (long)k*128 + j] = acc;
}

// ---------- ebW[l][j] = sum_d eb2[l][d]*NW1b[l][d][j] ----------
__global__ __launch_bounds__(128) void ebw_kernel(
    const void* __restrict__ eb2, const void* __restrict__ nw1,
    float* __restrict__ ebW, const int* __restrict__ flagp)
{
  const int isbf = *flagp;
  int l = blockIdx.x, j = threadIdx.x;
  long nb = (long)l*256*128 + 128*128;
  float acc = 0.f;
  for (int d=0; d<128; d++)
    acc += ldf(eb2, (long)l*128 + d, isbf) * ldf(nw1, nb + (long)d*128 + j, isbf);
  ebW[l*128+j] = acc;
}

// ---------- per-layer w2p = EW2 @ pw1[0:128], c2p = eb2 . pw1[0:128] ----------
__global__ __launch_bounds__(128) void w2p_kernel(
    const void* __restrict__ ew2, const void* __restrict__ eb2, const void* __restrict__ pw1,
    float* __restrict__ w2p, float* __restrict__ c2p, const int* __restrict__ flagp)
{
  const int isbf = *flagp;
  int l = blockIdx.x, i = threadIdx.x;
  long Woff = (long)l*128*128, poff = (long)l*129;
  float acc = 0.f;
  for (int j=0;j<128;j++) acc += ldf(ew2, Woff + (long)i*128 + j, isbf) * ldf(pw1, poff + j, isbf);
  w2p[l*128+i] = acc;
  __shared__ float red[128];
  red[i] = ldf(eb2, (long)l*128 + i, isbf) * ldf(pw1, poff + i, isbf);
  __syncthreads();
  for (int st=64; st>0; st>>=1){ if (i<st) red[i]+=red[i+st]; __syncthreads(); }
  if (i==0) c2p[l] = red[0];
}

__global__ void pparm_kernel(const void* pw1, const void* pb1, const void* pw2, const void* pb2,
                             float* pparm, const int* flagp)
{
  const int isbf = *flagp;
  int l = threadIdx.x;
  if (l < 4){
    pparm[l*4+0] = ldf(pw1, (long)l*129 + 128, isbf);
    pparm[l*4+1] = ldf(pb1, l, isbf);
    pparm[l*4+2] = ldf(pw2, l, isbf);
    pparm[l*4+3] = ldf(pb2, l, isbf);
  }
}

// ---------- CSR build: histogram, 3-stage scan, scatter ----------
__global__ __launch_bounds__(256) void hist_kernel(const int* __restrict__ tgt, int* __restrict__ cnt, int E){
  int i = blockIdx.x*256 + threadIdx.x;
  if (i < E) atomicAdd(&cnt[tgt[i]], 1);
}

__global__ __launch_bounds__(256) void bsum_kernel(const int* __restrict__ cnt, int* __restrict__ bsum, int N){
  int i = blockIdx.x*256 + threadIdx.x;
  int v = (i < N) ? cnt[i] : 0;
#pragma unroll
  for (int off=32; off; off>>=1) v += __shfl_down(v, off);
  __shared__ int ws[4];
  if ((threadIdx.x & 63) == 0) ws[threadIdx.x>>6] = v;
  __syncthreads();
  if (threadIdx.x == 0) bsum[blockIdx.x] = ws[0]+ws[1]+ws[2]+ws[3];
}

__global__ __launch_bounds__(256) void bscan_kernel(int* __restrict__ bsum, int nb){
  __shared__ int lds[256];
  int i = threadIdx.x;
  int v = (i < nb) ? bsum[i] : 0;
  lds[i] = v; __syncthreads();
#pragma unroll
  for (int off=1; off<256; off<<=1){
    int t = (i>=off)? lds[i-off] : 0; __syncthreads();
    lds[i] += t; __syncthreads();
  }
  if (i < nb) bsum[i] = lds[i] - v;  // exclusive prefix
}

__global__ __launch_bounds__(256) void csr_kernel(
    const int* __restrict__ cnt, const int* __restrict__ bsum,
    int* __restrict__ rowptr, int* __restrict__ cursor, float* __restrict__ degf, int N)
{
  __shared__ int lds[256];
  int i = blockIdx.x*256 + threadIdx.x;
  int c = (i < N) ? cnt[i] : 0;
  lds[threadIdx.x] = c; __syncthreads();
#pragma unroll
  for (int off=1; off<256; off<<=1){
    int t = (threadIdx.x>=off)? lds[threadIdx.x-off] : 0; __syncthreads();
    lds[threadIdx.x] += t; __syncthreads();
  }
  int run = bsum[blockIdx.x] + lds[threadIdx.x] - c;  // exclusive
  if (i < N){
    rowptr[i] = run; cursor[i] = run; degf[i] = (float)c;
    if (i == N-1) rowptr[N] = run + c;
  }
}

__global__ __launch_bounds__(256) void scatter_kernel(
    const int* __restrict__ src, const int* __restrict__ tgt,
    int* __restrict__ cursor, int* __restrict__ permsrc, int E)
{
  int e = blockIdx.x*256 + threadIdx.x;
  if (e >= E) return;
  int t = tgt[e];
  int p = atomicAdd(&cursor[t], 1);
  permsrc[p] = src[e];
}

// ---------- initial projection x = nf @ npw + npb (2 nodes/block) ----------
__global__ __launch_bounds__(256) void proj_kernel(
    const void* __restrict__ nf, const void* __restrict__ W, const void* __restrict__ bvec,
    u16* __restrict__ xb, int N, const int* __restrict__ flagp)
{
  const int isbf = *flagp;
  int n = blockIdx.x*2 + (threadIdx.x>>7), d = threadIdx.x & 127;
  if (n >= N) return;
  float acc = ldf(bvec, d, isbf);
#pragma unroll
  for (int f=0; f<12; f++) acc += ldf(nf, (long)n*12+f, isbf) * ldf(W, f*128+d, isbf);
  xb[(long)n*128+d] = f2b(acc);
}

__global__ __launch_bounds__(256) void cvtp_kernel(const void* __restrict__ pos, float* __restrict__ pf,
                                                   int n, const int* __restrict__ flagp){
  const int isbf = *flagp;
  int i = blockIdx.x*256 + threadIdx.x;
  if (i < n) pf[i] = ldf(pos, i, isbf);
}

// ---------- streaming A/B matmul: Ab = bf16(x@Wa+eb1), Bb = bf16(x@Wb) ----------
__global__ __launch_bounds__(256) void mm_ab_kernel(
    const u16* __restrict__ X, const u16* __restrict__ Wa, const u16* __restrict__ Wb,
    const void* __restrict__ bias, long bias_off,
    u16* __restrict__ Ab, u16* __restrict__ Bb, const int* __restrict__ flagp)
{
  extern __shared__ u16 wlds[];
  const int tid = threadIdx.x, wave = tid>>6, lane = tid&63;
  const int isbf = *flagp;
  const int lr = lane&15, lg = lane>>4;
  for (int i=tid; i<2048; i+=256){
    *(bf16x8*)(wlds + (long)i*8)          = *(const bf16x8*)(Wa + (long)i*8);
    *(bf16x8*)(wlds + 16384 + (long)i*8)  = *(const bf16x8*)(Wb + (long)i*8);
  }
  float biasv[8];
#pragma unroll
  for (int nt=0;nt<8;nt++) biasv[nt] = ldf(bias, bias_off + nt*16 + lr, isbf);
  __syncthreads();
  for (int tile = blockIdx.x*4 + wave; tile < NTILES; tile += MMGRID*4){
    const u16* xr = X + ((long)tile*16 + lr)*128;
    bf16x8 a[4];
#pragma unroll
    for (int kk=0;kk<4;kk++) a[kk] = *(const bf16x8*)(xr + kk*32 + lg*8);
    floatx4 accA[8], accB[8];
#pragma unroll
    for (int i=0;i<8;i++){ accA[i]=(floatx4){0,0,0,0}; accB[i]=(floatx4){0,0,0,0}; }
#pragma unroll
    for (int kk=0;kk<4;kk++){
#pragma unroll
      for (int nt=0;nt<8;nt++){
        bf16x8 ba = *(const bf16x8*)(wlds + ((kk*8+nt)*64 + lane)*8);
        accA[nt] = __builtin_amdgcn_mfma_f32_16x16x32_bf16(a[kk], ba, accA[nt], 0, 0, 0);
        bf16x8 bb = *(const bf16x8*)(wlds + 16384 + ((kk*8+nt)*64 + lane)*8);
        accB[nt] = __builtin_amdgcn_mfma_f32_16x16x32_bf16(a[kk], bb, accB[nt], 0, 0, 0);
      }
    }
#pragma unroll
    for (int r=0;r<4;r++){
      long row = (long)tile*16 + lg*4 + r;
#pragma unroll
      for (int nt=0;nt<8;nt++){
        int col = nt*16 + lr;
        Ab[row*128+col] = f2b(accA[nt][r] + biasv[nt]);
        Bb[row*128+col] = f2b(accB[nt][r]);
      }
    }
  }
}

// ---------- streaming hidden matmul: hb = bf16(silu(xb@NW1a + Hb@W12 + deg*ebW + nb1)) ----------
__global__ __launch_bounds__(256) void mm_hidden_kernel(
    const u16* __restrict__ X, const u16* __restrict__ H,
    const u16* __restrict__ W1, const u16* __restrict__ W2,
    const void* __restrict__ nb1, long nb1_off,
    const float* __restrict__ degf, const float* __restrict__ ebW,
    u16* __restrict__ hb, const int* __restrict__ flagp)
{
  extern __shared__ u16 wlds[];
  const int tid = threadIdx.x, wave = tid>>6, lane = tid&63;
  const int isbf = *flagp;
  const int lr = lane&15, lg = lane>>4;
  for (int i=tid; i<2048; i+=256){
    *(bf16x8*)(wlds + (long)i*8)          = *(const bf16x8*)(W1 + (long)i*8);
    *(bf16x8*)(wlds + 16384 + (long)i*8)  = *(const bf16x8*)(W2 + (long)i*8);
  }
  float nb1v[8], ebv[8];
#pragma unroll
  for (int nt=0;nt<8;nt++){ int col=nt*16+lr; nb1v[nt]=ldf(nb1, nb1_off+col, isbf); ebv[nt]=ebW[col]; }
  __syncthreads();
  for (int tile = blockIdx.x*4 + wave; tile < NTILES; tile += MMGRID*4){
    const u16* xr = X + ((long)tile*16 + lr)*128;
    const u16* hr = H + ((long)tile*16 + lr)*128;
    bf16x8 ax[4], ah[4];
#pragma unroll
    for (int kk=0;kk<4;kk++){
      ax[kk] = *(const bf16x8*)(xr + kk*32 + lg*8);
      ah[kk] = *(const bf16x8*)(hr + kk*32 + lg*8);
    }
    floatx4 acc[8];
#pragma unroll
    for (int i=0;i<8;i++) acc[i]=(floatx4){0,0,0,0};
#pragma unroll
    for (int kk=0;kk<4;kk++){
#pragma unroll
      for (int nt=0;nt<8;nt++){
        bf16x8 b1 = *(const bf16x8*)(wlds + ((kk*8+nt)*64 + lane)*8);
        acc[nt] = __builtin_amdgcn_mfma_f32_16x16x32_bf16(ax[kk], b1, acc[nt], 0, 0, 0);
        bf16x8 b2 = *(const bf16x8*)(wlds + 16384 + ((kk*8+nt)*64 + lane)*8);
        acc[nt] = __builtin_amdgcn_mfma_f32_16x16x32_bf16(ah[kk], b2, acc[nt], 0, 0, 0);
      }
    }
    float dv[4];
#pragma unroll
    for (int r=0;r<4;r++) dv[r] = degf[(long)tile*16 + lg*4 + r];
#pragma unroll
    for (int r=0;r<4;r++){
      long row = (long)tile*16 + lg*4 + r;
#pragma unroll
      for (int nt=0;nt<8;nt++){
        int col = nt*16 + lr;
        hb[row*128+col] = f2b(siluf(acc[nt][r] + nb1v[nt] + dv[r]*ebv[nt]));
      }
    }
  }
}

// ---------- streaming residual matmul (bf16 residual stream) ----------
// LN=0: xb = bf16(b2f(xb) + hb@NW2 + nb2).  LN=1: layernorm -> d_out.
template<int LN>
__global__ __launch_bounds__(256) void mm_res_kernel(
    const u16* __restrict__ H, const u16* __restrict__ W,
    const void* __restrict__ nb2, long nb2_off,
    u16* __restrict__ xb,
    const void* __restrict__ lng, const void* __restrict__ lnb, void* __restrict__ outp,
    const int* __restrict__ flagp)
{
  extern __shared__ u16 wlds[];
  const int tid = threadIdx.x, wave = tid>>6, lane = tid&63;
  const int isbf = *flagp;
  const int lr = lane&15, lg = lane>>4;
  for (int i=tid; i<2048; i+=256)
    *(bf16x8*)(wlds + (long)i*8) = *(const bf16x8*)(W + (long)i*8);
  float nb2v[8];
#pragma unroll
  for (int nt=0;nt<8;nt++) nb2v[nt] = ldf(nb2, nb2_off + nt*16 + lr, isbf);
  float gv[8], bvv[8];
  if (LN){
#pragma unroll
    for (int nt=0;nt<8;nt++){ int col=nt*16+lr; gv[nt]=ldf(lng,col,isbf); bvv[nt]=ldf(lnb,col,isbf); }
  }
  __syncthreads();
  for (int tile = blockIdx.x*4 + wave; tile < NTILES; tile += MMGRID*4){
    const u16* hr = H + ((long)tile*16 + lr)*128;
    bf16x8 a[4];
#pragma unroll
    for (int kk=0;kk<4;kk++) a[kk] = *(const bf16x8*)(hr + kk*32 + lg*8);
    floatx4 acc[8];
#pragma unroll
    for (int i=0;i<8;i++) acc[i]=(floatx4){0,0,0,0};
#pragma unroll
    for (int kk=0;kk<4;kk++){
#pragma unroll
      for (int nt=0;nt<8;nt++){
        bf16x8 b = *(const bf16x8*)(wlds + ((kk*8+nt)*64 + lane)*8);
        acc[nt] = __builtin_amdgcn_mfma_f32_16x16x32_bf16(a[kk], b, acc[nt], 0, 0, 0);
      }
    }
#pragma unroll
    for (int r=0;r<4;r++){
      long row = (long)tile*16 + lg*4 + r;
#pragma unroll
      for (int nt=0;nt<8;nt++){
        int col = nt*16 + lr;
        float v = acc[nt][r] + nb2v[nt] + b2f(xb[row*128+col]);
        acc[nt][r] = v;
        if (!LN) xb[row*128+col] = f2b(v);
      }
    }
    if (LN){
      float s[4] = {0,0,0,0}, q[4] = {0,0,0,0};
#pragma unroll
      for (int r=0;r<4;r++){
#pragma unroll
        for (int nt=0;nt<8;nt++){ float v = acc[nt][r]; s[r] += v; q[r] += v*v; }
      }
#pragma unroll
      for (int mask=1; mask<16; mask<<=1){
#pragma unroll
        for (int r=0;r<4;r++){ s[r] += __shfl_xor(s[r], mask); q[r] += __shfl_xor(q[r], mask); }
      }
#pragma unroll
      for (int r=0;r<4;r++){
        long row = (long)tile*16 + lg*4 + r;
        float mu = s[r]*(1.f/128.f);
        float var = q[r]*(1.f/128.f) - mu*mu;
        float inv = rsqrtf(var + 1e-5f);
#pragma unroll
        for (int nt=0;nt<8;nt++){
          int col = nt*16 + lr;
          float y = (acc[nt][r]-mu)*inv*gv[nt] + bvv[nt];
          if (isbf) ((u16*)outp)[row*128+col] = f2b(y);
          else      ((float*)outp)[row*128+col] = y;
        }
      }
    }
  }
}

// ---------- CSR aggregation: one wave per target node, chunked x4 (R5-proven) ----------
__global__ __launch_bounds__(256) void agg_kernel(
    const int* __restrict__ rowptr, const int* __restrict__ permsrc,
    const float* __restrict__ pf_in,
    const u16* __restrict__ A, const u16* __restrict__ B,
    const void* __restrict__ ew1, long w1c_off,
    const float* __restrict__ w2p, const float* __restrict__ c2pl,
    const float* __restrict__ pp,
    u16* __restrict__ Hb, float* __restrict__ pf_out, int N,
    const int* __restrict__ flagp)
{
  const int isbf = *flagp;
  int tid = threadIdx.x, lane = tid & 63;
  int t = blockIdx.x*4 + (tid>>6);
  if (t >= N) return;
  int tu = __builtin_amdgcn_readfirstlane(t);   // wave-uniform -> scalar loads
  float c0 = ldf(ew1, w1c_off + 2*lane,     isbf);
  float c1 = ldf(ew1, w1c_off + 2*lane + 1, isbf);
  float2 wp = *(const float2*)(w2p + 2*lane);
  float c2 = c2pl[0];
  float p0 = pp[0], p1 = pp[1], p2 = pp[2], p3 = pp[3];
  int jb = rowptr[tu], je = rowptr[tu+1];
  float2 pt = *(const float2*)(pf_in + 2*(long)tu);
  unsigned bv = *(const unsigned*)(B + (long)tu*128 + 2*lane);
  float b0 = b2f((u16)bv), b1 = b2f((u16)(bv>>16));
  float h0a = 0.f, h1a = 0.f, dpx = 0.f, dpy = 0.f;
  for (int j0 = jb; j0 < je; j0 += 4){
    int m = je - j0; if (m > 4) m = 4;
    int s[4]; float2 ps[4]; unsigned av[4];
    float part[4], dist[4], dxv[4], dyv[4];
#pragma unroll
    for (int c=0;c<4;c++) if (c<m) s[c] = permsrc[j0+c];
#pragma unroll
    for (int c=0;c<4;c++) if (c<m){
      ps[c] = *(const float2*)(pf_in + 2*(long)s[c]);
      av[c] = *(const unsigned*)(A + (long)s[c]*128 + 2*lane);
    }
#pragma unroll
    for (int c=0;c<4;c++){
      if (c<m){
        float dx = pt.x - ps[c].x, dy = pt.y - ps[c].y;
        float d2 = dx*dx + dy*dy;
        float dd = __builtin_amdgcn_sqrtf(d2);
        float h0 = siluf(b2f((u16)av[c])       + b0 + dd*c0);
        float h1 = siluf(b2f((u16)(av[c]>>16)) + b1 + dd*c1);
        h0a += h0; h1a += h1;
        part[c] = h0*wp.x + h1*wp.y;
        dist[c] = dd; dxv[c] = dx; dyv[c] = dy;
      } else part[c] = 0.f;
    }
#pragma unroll
    for (int off=32; off; off>>=1){
#pragma unroll
      for (int c=0;c<4;c++) part[c] += __shfl_xor(part[c], off);
    }
#pragma unroll
    for (int c=0;c<4;c++){
      if (c<m){
        float spre = part[c] + c2 + dist[c]*p0 + p1;
        float pwv  = siluf(spre)*p2 + p3;
        float inv  = __builtin_amdgcn_rcpf(dist[c] + 1e-6f);
        dpx += dxv[c]*inv*pwv; dpy += dyv[c]*inv*pwv;
      }
    }
  }
  *(unsigned*)(Hb + (long)tu*128 + 2*lane) = (unsigned)f2b(h0a) | ((unsigned)f2b(h1a)<<16);
  if (lane == 0){
    float2 o; o.x = pt.x + dpx; o.y = pt.y + dpy;
    *(float2*)(pf_out + 2*(long)tu) = o;
  }
}

extern "C" void kernel_launch(void* const* d_in, const int* in_sizes, int n_in,
                              void* d_out, int out_size, void* d_ws, size_t ws_size,
                              hipStream_t stream)
{
  const void* nf  = d_in[0];
  const void* pos = d_in[1];
  const void* npw = d_in[3];
  const void* npb = d_in[4];
  const void* ew1 = d_in[7];
  const void* eb1 = d_in[8];
  const void* ew2 = d_in[9];
  const void* eb2 = d_in[10];
  const void* nw1 = d_in[11];
  const void* nb1 = d_in[12];
  const void* nw2 = d_in[13];
  const void* nb2 = d_in[14];
  const void* pw1 = d_in[15];
  const void* pb1 = d_in[16];
  const void* pw2 = d_in[17];
  const void* pb2 = d_in[18];
  const void* lng = d_in[19];
  const void* lnb = d_in[20];
  const int* eidx = (const int*)d_in[21];
  const int N = NNODES, E = NEDGES;
  const int* srcp = eidx;
  const int* tgtp = eidx + E;

  char* w = (char*)d_ws;
  size_t off = 0;
  auto alloc = [&](size_t bytes)->char* { char* p = w + off; off += (bytes + 255)/256*256; return p; };
  u16*   xb    = (u16*)  alloc((size_t)N*128*2);
  u16*   Ab    = (u16*)  alloc((size_t)N*128*2);
  u16*   Bb    = (u16*)  alloc((size_t)N*128*2);
  u16*   Hb    = (u16*)  alloc((size_t)N*128*2);
  float* pf0   = (float*)alloc((size_t)N*2*4);
  float* pf1   = (float*)alloc((size_t)N*2*4);
  int*   cnt   = (int*)  alloc((size_t)N*4);
  int*   rowptr= (int*)  alloc((size_t)(N+1)*4);
  int*   cursor= (int*)  alloc((size_t)N*4);
  float* degf  = (float*)alloc((size_t)N*4);
  int*   perm  = (int*)  alloc((size_t)E*4);
  int*   bsum  = (int*)  alloc(256*4);
  u16*   pk    = (u16*)  alloc((size_t)28*16384*2);
  float* W12f  = (float*)alloc((size_t)4*16384*4);
  float* ebW   = (float*)alloc(4*128*4);
  float* w2p   = (float*)alloc(4*128*4);
  float* c2p   = (float*)alloc(4*4);
  float* pparm = (float*)alloc(16*4);
  int*   flag  = (int*)  alloc(4);
  u16* hb = Ab;   // Ab dead after agg_kernel; rewritten by next mm_ab

  const int NB = (N + 255)/256;  // 196 <= 256
  detect_kernel<<<1, 64, 0, stream>>>(lng, flag);
  hipMemsetAsync(cnt, 0, (size_t)N*4, stream);
  hist_kernel<<<(E+255)/256, 256, 0, stream>>>(tgtp, cnt, E);
  bsum_kernel<<<NB, 256, 0, stream>>>(cnt, bsum, N);
  bscan_kernel<<<1, 256, 0, stream>>>(bsum, NB);
  csr_kernel<<<NB, 256, 0, stream>>>(cnt, bsum, rowptr, cursor, degf, N);
  scatter_kernel<<<(E+255)/256, 256, 0, stream>>>(srcp, tgtp, cursor, perm, E);
  pack_kernel<<<192, 256, 0, stream>>>(ew1, ew2, nw1, nw2, pk, flag);
  w12_kernel<<<512, 128, 0, stream>>>(ew2, nw1, W12f, flag);
  ebw_kernel<<<4, 128, 0, stream>>>(eb2, nw1, ebW, flag);
  pack2_kernel<<<32, 256, 0, stream>>>(W12f, pk);
  w2p_kernel<<<4, 128, 0, stream>>>(ew2, eb2, pw1, w2p, c2p, flag);
  pparm_kernel<<<1, 64, 0, stream>>>(pw1, pb1, pw2, pb2, pparm, flag);
  proj_kernel<<<(N+1)/2, 256, 0, stream>>>(nf, npw, npb, xb, N, flag);
  cvtp_kernel<<<(2*N+255)/256, 256, 0, stream>>>(pos, pf0, 2*N, flag);

  // layer 0 A/B from projected x
  mm_ab_kernel<<<MMGRID, 256, 65536, stream>>>(xb, pk + 0*16384, pk + 1*16384,
                                               eb1, 0, Ab, Bb, flag);
  for (int l = 0; l < 4; l++){
    const u16* NW1a = pk + (l*6+3)*16384;
    const u16* NW2p = pk + (l*6+5)*16384;
    const u16* W12p = pk + (24+l)*16384;
    float* pin  = (l & 1) ? pf1 : pf0;
    float* pout = (l & 1) ? pf0 : pf1;

    agg_kernel<<<(N+3)/4, 256, 0, stream>>>(
        rowptr, perm, pin, Ab, Bb,
        ew1, (long)l*257*128 + 256*128,
        w2p + l*128, c2p + l, pparm + l*4,
        Hb, pout, N, flag);
    mm_hidden_kernel<<<MMGRID, 256, 65536, stream>>>(
        xb, Hb, NW1a, W12p, nb1, (long)l*128, degf, ebW + l*128, hb, flag);
    if (l < 3){
      mm_res_kernel<0><<<MMGRID, 256, 32768, stream>>>(
          hb, NW2p, nb2, (long)l*128, xb, nullptr, nullptr, nullptr, flag);
      mm_ab_kernel<<<MMGRID, 256, 65536, stream>>>(
          xb, pk + ((l+1)*6+0)*16384, pk + ((l+1)*6+1)*16384,
          eb1, (long)(l+1)*128, Ab, Bb, flag);
    } else {
      mm_res_kernel<1><<<MMGRID, 256, 32768, stream>>>(
          hb, NW2p, nb2, (long)l*128, xb, lng, lnb, d_out, flag);
    }
  }
}

// Round 11
// 525.380 us; speedup vs baseline: 1.6125x; 1.1031x over previous
//
#include <hip/hip_runtime.h>
#include <hip/hip_bf16.h>

// EGNN encoder, N=50000, E=250000, D=128, L=4. bf16 inputs/output (verified R2).
// R3: CSR-by-tgt aggregation (no atomics), EW2@NW1b folding.
// R4: 3-stage parallel CSR scan.  R5: agg chunked x4 + fast rcp (VGPR 32 — occupancy
//     is the latency-hider; R8/R9 both regressed by killing it).
// R7: weight-stationary streaming matmuls.  R10: bf16-only residual stream.
// R11: 8 setup kernels merged into one phase-partitioned kernel (w12 writes
//     packed directly; pack2+W12f eliminated); mm_res grid 512->1024 (32KB LDS
//     allows 4 blocks/CU). Dispatches 31 -> 24.

#define NNODES 50000
#define NEDGES 250000
#define NTILES 3125   // 50000/16 exactly, no tail
#define MMGRID 512
#define RGRID  1024

typedef unsigned short u16;
typedef __attribute__((ext_vector_type(8))) short bf16x8;
typedef __attribute__((ext_vector_type(4))) float floatx4;

__device__ __forceinline__ float b2f(u16 h){ unsigned u=((unsigned)h)<<16; float f; __builtin_memcpy(&f,&u,4); return f; }
__device__ __forceinline__ u16 f2b(float f){ unsigned u; __builtin_memcpy(&u,&f,4); u = u + 0x7FFFu + ((u>>16)&1u); return (u16)(u>>16); }
__device__ __forceinline__ float siluf(float x){ return x*__builtin_amdgcn_rcpf(1.f+__expf(-x)); }
__device__ __forceinline__ float ldf(const void* p, long i, int isbf){
  return isbf ? b2f(((const u16*)p)[i]) : ((const float*)p)[i];
}

__global__ void detect_kernel(const void* lng, int* flag){
  if (threadIdx.x==0 && blockIdx.x==0) *flag = (((const u16*)lng)[0] != 0) ? 1 : 0;
}

// ---------- merged setup: phases partitioned by blockIdx ----------
// [0,192):      pack 24 weight matrices into MFMA B-frag order
// [192,704):    W12 = EW2@NW1b computed AND written directly in packed order (chunks 24..27)
// [704,708):    ebW[l] = eb2@NW1b
// [708,712):    w2p[l] = EW2@pw1, c2p[l] = eb2.pw1
// 712:          pparm
// [713,25713):  proj x = nf@npw + npb (2 nodes/block)
// [25713,26104):cvtp pos -> fp32
#define SU_W12   192
#define SU_EBW   704
#define SU_W2P   708
#define SU_PPARM 712
#define SU_PROJ  713
#define SU_CVTP  25713
#define SU_END   26104
__global__ __launch_bounds__(256) void setup_kernel(
    const void* __restrict__ ew1, const void* __restrict__ ew2,
    const void* __restrict__ nw1, const void* __restrict__ nw2,
    u16* __restrict__ packed,
    const void* __restrict__ eb2, const void* __restrict__ pw1,
    const void* __restrict__ pb1, const void* __restrict__ pw2v, const void* __restrict__ pb2,
    float* __restrict__ w2p, float* __restrict__ c2p, float* __restrict__ pparm,
    float* __restrict__ ebW,
    const void* __restrict__ nf, const void* __restrict__ npw, const void* __restrict__ npb,
    u16* __restrict__ xb,
    const void* __restrict__ pos, float* __restrict__ pf,
    const int* __restrict__ flagp)
{
  const int isbf = *flagp;
  const int b = blockIdx.x, tid = threadIdx.x;
  __shared__ float red[128];
  if (b < SU_W12){
    // ---- pack 24 matrices ----
    int t = b*256 + tid;
    int m = t >> 11; int r = t & 2047;
    int lane = r & 63; int ntk = r >> 6;
    int kk = ntk >> 3, nt = ntk & 7;
    int l = m/6, w = m%6;
    const void* src; long off;
    switch(w){
      case 0: src=ew1; off=(long)l*257*128;            break; // W1a
      case 1: src=ew1; off=(long)l*257*128 + 128*128;  break; // W1b
      case 2: src=ew2; off=(long)l*128*128;            break; // EW2 (unused, kept for layout)
      case 3: src=nw1; off=(long)l*256*128;            break; // NW1a
      case 4: src=nw1; off=(long)l*256*128 + 128*128;  break; // NW1b (unused)
      default:src=nw2; off=(long)l*128*128;            break; // NW2
    }
    int c  = nt*16 + (lane & 15);
    int k0 = kk*32 + (lane >> 4)*8;
    u16 vals[8];
#pragma unroll
    for (int j=0;j<8;j++){
      long idx = off + (long)(k0+j)*128 + c;
      vals[j] = isbf ? ((const u16*)src)[idx] : f2b(((const float*)src)[idx]);
    }
    bf16x8 v; __builtin_memcpy(&v, vals, 16);
    *(bf16x8*)(packed + (long)t*8) = v;
  } else if (b < SU_EBW){
    // ---- W12[l][k][j] -> packed chunk 24+l, fragment position ----
    int bb = b - SU_W12;
    int l = bb >> 7, k = bb & 127;
    if (tid < 128){
      int j = tid;
      long e2 = (long)l*16384 + (long)k*128;
      long nb = (long)l*256*128 + 128*128;
      float acc = 0.f;
      for (int d=0; d<128; d++)
        acc += ldf(ew2, e2 + d, isbf) * ldf(nw1, nb + (long)d*128 + j, isbf);
      int kk = k>>5, lane = ((k>>3)&3)*16 + (j&15), nt = j>>4, jj = k&7;
      packed[(long)(24+l)*16384 + (long)((kk*8+nt)*64 + lane)*8 + jj] = f2b(acc);
    }
  } else if (b < SU_W2P){
    int l = b - SU_EBW;
    if (tid < 128){
      int j = tid;
      long nb = (long)l*256*128 + 128*128;
      float acc = 0.f;
      for (int d=0; d<128; d++)
        acc += ldf(eb2, (long)l*128 + d, isbf) * ldf(nw1, nb + (long)d*128 + j, isbf);
      ebW[l*128+j] = acc;
    }
  } else if (b < SU_PPARM){
    int l = b - SU_W2P;
    int i = tid;
    long Woff = (long)l*128*128, poff = (long)l*129;
    if (i < 128){
      float acc = 0.f;
      for (int j=0;j<128;j++) acc += ldf(ew2, Woff + (long)i*128 + j, isbf) * ldf(pw1, poff + j, isbf);
      w2p[l*128+i] = acc;
      red[i] = ldf(eb2, (long)l*128 + i, isbf) * ldf(pw1, poff + i, isbf);
    }
    __syncthreads();
    for (int st=64; st>0; st>>=1){ if (i<st) red[i]+=red[i+st]; __syncthreads(); }
    if (i==0) c2p[l] = red[0];
  } else if (b == SU_PPARM){
    int l = tid;
    if (l < 4){
      pparm[l*4+0] = ldf(pw1, (long)l*129 + 128, isbf);
      pparm[l*4+1] = ldf(pb1, l, isbf);
      pparm[l*4+2] = ldf(pw2v, l, isbf);
      pparm[l*4+3] = ldf(pb2, l, isbf);
    }
  } else if (b < SU_CVTP){
    int n = (b - SU_PROJ)*2 + (tid>>7), d = tid & 127;
    if (n < NNODES){
      float acc = ldf(npb, d, isbf);
#pragma unroll
      for (int f=0; f<12; f++) acc += ldf(nf, (long)n*12+f, isbf) * ldf(npw, f*128+d, isbf);
      xb[(long)n*128+d] = f2b(acc);
    }
  } else {
    int i = (b - SU_CVTP)*256 + tid;
    if (i < 2*NNODES) pf[i] = ldf(pos, i, isbf);
  }
}

// ---------- CSR build: histogram, 3-stage scan, scatter ----------
__global__ __launch_bounds__(256) void hist_kernel(const int* __restrict__ tgt, int* __restrict__ cnt, int E){
  int i = blockIdx.x*256 + threadIdx.x;
  if (i < E) atomicAdd(&cnt[tgt[i]], 1);
}

__global__ __launch_bounds__(256) void bsum_kernel(const int* __restrict__ cnt, int* __restrict__ bsum, int N){
  int i = blockIdx.x*256 + threadIdx.x;
  int v = (i < N) ? cnt[i] : 0;
#pragma unroll
  for (int off=32; off; off>>=1) v += __shfl_down(v, off);
  __shared__ int ws[4];
  if ((threadIdx.x & 63) == 0) ws[threadIdx.x>>6] = v;
  __syncthreads();
  if (threadIdx.x == 0) bsum[blockIdx.x] = ws[0]+ws[1]+ws[2]+ws[3];
}

__global__ __launch_bounds__(256) void bscan_kernel(int* __restrict__ bsum, int nb){
  __shared__ int lds[256];
  int i = threadIdx.x;
  int v = (i < nb) ? bsum[i] : 0;
  lds[i] = v; __syncthreads();
#pragma unroll
  for (int off=1; off<256; off<<=1){
    int t = (i>=off)? lds[i-off] : 0; __syncthreads();
    lds[i] += t; __syncthreads();
  }
  if (i < nb) bsum[i] = lds[i] - v;  // exclusive prefix
}

__global__ __launch_bounds__(256) void csr_kernel(
    const int* __restrict__ cnt, const int* __restrict__ bsum,
    int* __restrict__ rowptr, int* __restrict__ cursor, float* __restrict__ degf, int N)
{
  __shared__ int lds[256];
  int i = blockIdx.x*256 + threadIdx.x;
  int c = (i < N) ? cnt[i] : 0;
  lds[threadIdx.x] = c; __syncthreads();
#pragma unroll
  for (int off=1; off<256; off<<=1){
    int t = (threadIdx.x>=off)? lds[threadIdx.x-off] : 0; __syncthreads();
    lds[threadIdx.x] += t; __syncthreads();
  }
  int run = bsum[blockIdx.x] + lds[threadIdx.x] - c;  // exclusive
  if (i < N){
    rowptr[i] = run; cursor[i] = run; degf[i] = (float)c;
    if (i == N-1) rowptr[N] = run + c;
  }
}

__global__ __launch_bounds__(256) void scatter_kernel(
    const int* __restrict__ src, const int* __restrict__ tgt,
    int* __restrict__ cursor, int* __restrict__ permsrc, int E)
{
  int e = blockIdx.x*256 + threadIdx.x;
  if (e >= E) return;
  int t = tgt[e];
  int p = atomicAdd(&cursor[t], 1);
  permsrc[p] = src[e];
}

// ---------- streaming A/B matmul: Ab = bf16(x@Wa+eb1), Bb = bf16(x@Wb) ----------
__global__ __launch_bounds__(256) void mm_ab_kernel(
    const u16* __restrict__ X, const u16* __restrict__ Wa, const u16* __restrict__ Wb,
    const void* __restrict__ bias, long bias_off,
    u16* __restrict__ Ab, u16* __restrict__ Bb, const int* __restrict__ flagp)
{
  extern __shared__ u16 wlds[];
  const int tid = threadIdx.x, wave = tid>>6, lane = tid&63;
  const int isbf = *flagp;
  const int lr = lane&15, lg = lane>>4;
  for (int i=tid; i<2048; i+=256){
    *(bf16x8*)(wlds + (long)i*8)          = *(const bf16x8*)(Wa + (long)i*8);
    *(bf16x8*)(wlds + 16384 + (long)i*8)  = *(const bf16x8*)(Wb + (long)i*8);
  }
  float biasv[8];
#pragma unroll
  for (int nt=0;nt<8;nt++) biasv[nt] = ldf(bias, bias_off + nt*16 + lr, isbf);
  __syncthreads();
  for (int tile = blockIdx.x*4 + wave; tile < NTILES; tile += MMGRID*4){
    const u16* xr = X + ((long)tile*16 + lr)*128;
    bf16x8 a[4];
#pragma unroll
    for (int kk=0;kk<4;kk++) a[kk] = *(const bf16x8*)(xr + kk*32 + lg*8);
    floatx4 accA[8], accB[8];
#pragma unroll
    for (int i=0;i<8;i++){ accA[i]=(floatx4){0,0,0,0}; accB[i]=(floatx4){0,0,0,0}; }
#pragma unroll
    for (int kk=0;kk<4;kk++){
#pragma unroll
      for (int nt=0;nt<8;nt++){
        bf16x8 ba = *(const bf16x8*)(wlds + ((kk*8+nt)*64 + lane)*8);
        accA[nt] = __builtin_amdgcn_mfma_f32_16x16x32_bf16(a[kk], ba, accA[nt], 0, 0, 0);
        bf16x8 bb = *(const bf16x8*)(wlds + 16384 + ((kk*8+nt)*64 + lane)*8);
        accB[nt] = __builtin_amdgcn_mfma_f32_16x16x32_bf16(a[kk], bb, accB[nt], 0, 0, 0);
      }
    }
#pragma unroll
    for (int r=0;r<4;r++){
      long row = (long)tile*16 + lg*4 + r;
#pragma unroll
      for (int nt=0;nt<8;nt++){
        int col = nt*16 + lr;
        Ab[row*128+col] = f2b(accA[nt][r] + biasv[nt]);
        Bb[row*128+col] = f2b(accB[nt][r]);
      }
    }
  }
}

// ---------- streaming hidden matmul: hb = bf16(silu(xb@NW1a + Hb@W12 + deg*ebW + nb1)) ----------
__global__ __launch_bounds__(256) void mm_hidden_kernel(
    const u16* __restrict__ X, const u16* __restrict__ H,
    const u16* __restrict__ W1, const u16* __restrict__ W2,
    const void* __restrict__ nb1, long nb1_off,
    const float* __restrict__ degf, const float* __restrict__ ebW,
    u16* __restrict__ hb, const int* __restrict__ flagp)
{
  extern __shared__ u16 wlds[];
  const int tid = threadIdx.x, wave = tid>>6, lane = tid&63;
  const int isbf = *flagp;
  const int lr = lane&15, lg = lane>>4;
  for (int i=tid; i<2048; i+=256){
    *(bf16x8*)(wlds + (long)i*8)          = *(const bf16x8*)(W1 + (long)i*8);
    *(bf16x8*)(wlds + 16384 + (long)i*8)  = *(const bf16x8*)(W2 + (long)i*8);
  }
  float nb1v[8], ebv[8];
#pragma unroll
  for (int nt=0;nt<8;nt++){ int col=nt*16+lr; nb1v[nt]=ldf(nb1, nb1_off+col, isbf); ebv[nt]=ebW[col]; }
  __syncthreads();
  for (int tile = blockIdx.x*4 + wave; tile < NTILES; tile += MMGRID*4){
    const u16* xr = X + ((long)tile*16 + lr)*128;
    const u16* hr = H + ((long)tile*16 + lr)*128;
    bf16x8 ax[4], ah[4];
#pragma unroll
    for (int kk=0;kk<4;kk++){
      ax[kk] = *(const bf16x8*)(xr + kk*32 + lg*8);
      ah[kk] = *(const bf16x8*)(hr + kk*32 + lg*8);
    }
    floatx4 acc[8];
#pragma unroll
    for (int i=0;i<8;i++) acc[i]=(floatx4){0,0,0,0};
#pragma unroll
    for (int kk=0;kk<4;kk++){
#pragma unroll
      for (int nt=0;nt<8;nt++){
        bf16x8 b1 = *(const bf16x8*)(wlds + ((kk*8+nt)*64 + lane)*8);
        acc[nt] = __builtin_amdgcn_mfma_f32_16x16x32_bf16(ax[kk], b1, acc[nt], 0, 0, 0);
        bf16x8 b2 = *(const bf16x8*)(wlds + 16384 + ((kk*8+nt)*64 + lane)*8);
        acc[nt] = __builtin_amdgcn_mfma_f32_16x16x32_bf16(ah[kk], b2, acc[nt], 0, 0, 0);
      }
    }
    float dv[4];
#pragma unroll
    for (int r=0;r<4;r++) dv[r] = degf[(long)tile*16 + lg*4 + r];
#pragma unroll
    for (int r=0;r<4;r++){
      long row = (long)tile*16 + lg*4 + r;
#pragma unroll
      for (int nt=0;nt<8;nt++){
        int col = nt*16 + lr;
        hb[row*128+col] = f2b(siluf(acc[nt][r] + nb1v[nt] + dv[r]*ebv[nt]));
      }
    }
  }
}

// ---------- streaming residual matmul (bf16 residual stream), grid RGRID ----------
// LN=0: xb = bf16(b2f(xb) + hb@NW2 + nb2).  LN=1: layernorm -> d_out.
template<int LN>
__global__ __launch_bounds__(256) void mm_res_kernel(
    const u16* __restrict__ H, const u16* __restrict__ W,
    const void* __restrict__ nb2, long nb2_off,
    u16* __restrict__ xb,
    const void* __restrict__ lng, const void* __restrict__ lnb, void* __restrict__ outp,
    const int* __restrict__ flagp)
{
  extern __shared__ u16 wlds[];
  const int tid = threadIdx.x, wave = tid>>6, lane = tid&63;
  const int isbf = *flagp;
  const int lr = lane&15, lg = lane>>4;
  for (int i=tid; i<2048; i+=256)
    *(bf16x8*)(wlds + (long)i*8) = *(const bf16x8*)(W + (long)i*8);
  float nb2v[8];
#pragma unroll
  for (int nt=0;nt<8;nt++) nb2v[nt] = ldf(nb2, nb2_off + nt*16 + lr, isbf);
  float gv[8], bvv[8];
  if (LN){
#pragma unroll
    for (int nt=0;nt<8;nt++){ int col=nt*16+lr; gv[nt]=ldf(lng,col,isbf); bvv[nt]=ldf(lnb,col,isbf); }
  }
  __syncthreads();
  for (int tile = blockIdx.x*4 + wave; tile < NTILES; tile += RGRID*4){
    const u16* hr = H + ((long)tile*16 + lr)*128;
    bf16x8 a[4];
#pragma unroll
    for (int kk=0;kk<4;kk++) a[kk] = *(const bf16x8*)(hr + kk*32 + lg*8);
    floatx4 acc[8];
#pragma unroll
    for (int i=0;i<8;i++) acc[i]=(floatx4){0,0,0,0};
#pragma unroll
    for (int kk=0;kk<4;kk++){
#pragma unroll
      for (int nt=0;nt<8;nt++){
        bf16x8 b = *(const bf16x8*)(wlds + ((kk*8+nt)*64 + lane)*8);
        acc[nt] = __builtin_amdgcn_mfma_f32_16x16x32_bf16(a[kk], b, acc[nt], 0, 0, 0);
      }
    }
#pragma unroll
    for (int r=0;r<4;r++){
      long row = (long)tile*16 + lg*4 + r;
#pragma unroll
      for (int nt=0;nt<8;nt++){
        int col = nt*16 + lr;
        float v = acc[nt][r] + nb2v[nt] + b2f(xb[row*128+col]);
        acc[nt][r] = v;
        if (!LN) xb[row*128+col] = f2b(v);
      }
    }
    if (LN){
      float s[4] = {0,0,0,0}, q[4] = {0,0,0,0};
#pragma unroll
      for (int r=0;r<4;r++){
#pragma unroll
        for (int nt=0;nt<8;nt++){ float v = acc[nt][r]; s[r] += v; q[r] += v*v; }
      }
#pragma unroll
      for (int mask=1; mask<16; mask<<=1){
#pragma unroll
        for (int r=0;r<4;r++){ s[r] += __shfl_xor(s[r], mask); q[r] += __shfl_xor(q[r], mask); }
      }
#pragma unroll
      for (int r=0;r<4;r++){
        long row = (long)tile*16 + lg*4 + r;
        float mu = s[r]*(1.f/128.f);
        float var = q[r]*(1.f/128.f) - mu*mu;
        float inv = rsqrtf(var + 1e-5f);
#pragma unroll
        for (int nt=0;nt<8;nt++){
          int col = nt*16 + lr;
          float y = (acc[nt][r]-mu)*inv*gv[nt] + bvv[nt];
          if (isbf) ((u16*)outp)[row*128+col] = f2b(y);
          else      ((float*)outp)[row*128+col] = y;
        }
      }
    }
  }
}

// ---------- CSR aggregation: one wave per target node, chunked x4 (R5-proven) ----------
__global__ __launch_bounds__(256) void agg_kernel(
    const int* __restrict__ rowptr, const int* __restrict__ permsrc,
    const float* __restrict__ pf_in,
    const u16* __restrict__ A, const u16* __restrict__ B,
    const void* __restrict__ ew1, long w1c_off,
    const float* __restrict__ w2p, const float* __restrict__ c2pl,
    const float* __restrict__ pp,
    u16* __restrict__ Hb, float* __restrict__ pf_out, int N,
    const int* __restrict__ flagp)
{
  const int isbf = *flagp;
  int tid = threadIdx.x, lane = tid & 63;
  int t = blockIdx.x*4 + (tid>>6);
  if (t >= N) return;
  int tu = __builtin_amdgcn_readfirstlane(t);   // wave-uniform -> scalar loads
  float c0 = ldf(ew1, w1c_off + 2*lane,     isbf);
  float c1 = ldf(ew1, w1c_off + 2*lane + 1, isbf);
  float2 wp = *(const float2*)(w2p + 2*lane);
  float c2 = c2pl[0];
  float p0 = pp[0], p1 = pp[1], p2 = pp[2], p3 = pp[3];
  int jb = rowptr[tu], je = rowptr[tu+1];
  float2 pt = *(const float2*)(pf_in + 2*(long)tu);
  unsigned bv = *(const unsigned*)(B + (long)tu*128 + 2*lane);
  float b0 = b2f((u16)bv), b1 = b2f((u16)(bv>>16));
  float h0a = 0.f, h1a = 0.f, dpx = 0.f, dpy = 0.f;
  for (int j0 = jb; j0 < je; j0 += 4){
    int m = je - j0; if (m > 4) m = 4;
    int s[4]; float2 ps[4]; unsigned av[4];
    float part[4], dist[4], dxv[4], dyv[4];
#pragma unroll
    for (int c=0;c<4;c++) if (c<m) s[c] = permsrc[j0+c];
#pragma unroll
    for (int c=0;c<4;c++) if (c<m){
      ps[c] = *(const float2*)(pf_in + 2*(long)s[c]);
      av[c] = *(const unsigned*)(A + (long)s[c]*128 + 2*lane);
    }
#pragma unroll
    for (int c=0;c<4;c++){
      if (c<m){
        float dx = pt.x - ps[c].x, dy = pt.y - ps[c].y;
        float d2 = dx*dx + dy*dy;
        float dd = __builtin_amdgcn_sqrtf(d2);
        float h0 = siluf(b2f((u16)av[c])       + b0 + dd*c0);
        float h1 = siluf(b2f((u16)(av[c]>>16)) + b1 + dd*c1);
        h0a += h0; h1a += h1;
        part[c] = h0*wp.x + h1*wp.y;
        dist[c] = dd; dxv[c] = dx; dyv[c] = dy;
      } else part[c] = 0.f;
    }
#pragma unroll
    for (int off=32; off; off>>=1){
#pragma unroll
      for (int c=0;c<4;c++) part[c] += __shfl_xor(part[c], off);
    }
#pragma unroll
    for (int c=0;c<4;c++){
      if (c<m){
        float spre = part[c] + c2 + dist[c]*p0 + p1;
        float pwv  = siluf(spre)*p2 + p3;
        float inv  = __builtin_amdgcn_rcpf(dist[c] + 1e-6f);
        dpx += dxv[c]*inv*pwv; dpy += dyv[c]*inv*pwv;
      }
    }
  }
  *(unsigned*)(Hb + (long)tu*128 + 2*lane) = (unsigned)f2b(h0a) | ((unsigned)f2b(h1a)<<16);
  if (lane == 0){
    float2 o; o.x = pt.x + dpx; o.y = pt.y + dpy;
    *(float2*)(pf_out + 2*(long)tu) = o;
  }
}

extern "C" void kernel_launch(void* const* d_in, const int* in_sizes, int n_in,
                              void* d_out, int out_size, void* d_ws, size_t ws_size,
                              hipStream_t stream)
{
  const void* nf  = d_in[0];
  const void* pos = d_in[1];
  const void* npw = d_in[3];
  const void* npb = d_in[4];
  const void* ew1 = d_in[7];
  const void* eb1 = d_in[8];
  const void* ew2 = d_in[9];
  const void* eb2 = d_in[10];
  const void* nw1 = d_in[11];
  const void* nb1 = d_in[12];
  const void* nw2 = d_in[13];
  const void* nb2 = d_in[14];
  const void* pw1 = d_in[15];
  const void* pb1 = d_in[16];
  const void* pw2 = d_in[17];
  const void* pb2 = d_in[18];
  const void* lng = d_in[19];
  const void* lnb = d_in[20];
  const int* eidx = (const int*)d_in[21];
  const int N = NNODES, E = NEDGES;
  const int* srcp = eidx;
  const int* tgtp = eidx + E;

  char* w = (char*)d_ws;
  size_t off = 0;
  auto alloc = [&](size_t bytes)->char* { char* p = w + off; off += (bytes + 255)/256*256; return p; };
  u16*   xb    = (u16*)  alloc((size_t)N*128*2);
  u16*   Ab    = (u16*)  alloc((size_t)N*128*2);
  u16*   Bb    = (u16*)  alloc((size_t)N*128*2);
  u16*   Hb    = (u16*)  alloc((size_t)N*128*2);
  float* pf0   = (float*)alloc((size_t)N*2*4);
  float* pf1   = (float*)alloc((size_t)N*2*4);
  int*   cnt   = (int*)  alloc((size_t)N*4);
  int*   rowptr= (int*)  alloc((size_t)(N+1)*4);
  int*   cursor= (int*)  alloc((size_t)N*4);
  float* degf  = (float*)alloc((size_t)N*4);
  int*   perm  = (int*)  alloc((size_t)E*4);
  int*   bsum  = (int*)  alloc(256*4);
  u16*   pk    = (u16*)  alloc((size_t)28*16384*2);
  float* ebW   = (float*)alloc(4*128*4);
  float* w2p   = (float*)alloc(4*128*4);
  float* c2p   = (float*)alloc(4*4);
  float* pparm = (float*)alloc(16*4);
  int*   flag  = (int*)  alloc(4);
  u16* hb = Ab;   // Ab dead after agg_kernel; rewritten by next mm_ab

  const int NB = (N + 255)/256;  // 196 <= 256
  detect_kernel<<<1, 64, 0, stream>>>(lng, flag);
  hipMemsetAsync(cnt, 0, (size_t)N*4, stream);
  hist_kernel<<<(E+255)/256, 256, 0, stream>>>(tgtp, cnt, E);
  bsum_kernel<<<NB, 256, 0, stream>>>(cnt, bsum, N);
  bscan_kernel<<<1, 256, 0, stream>>>(bsum, NB);
  csr_kernel<<<NB, 256, 0, stream>>>(cnt, bsum, rowptr, cursor, degf, N);
  scatter_kernel<<<(E+255)/256, 256, 0, stream>>>(srcp, tgtp, cursor, perm, E);
  setup_kernel<<<SU_END, 256, 0, stream>>>(
      ew1, ew2, nw1, nw2, pk,
      eb2, pw1, pb1, pw2, pb2,
      w2p, c2p, pparm, ebW,
      nf, npw, npb, xb,
      pos, pf0, flag);

  // layer 0 A/B from projected x
  mm_ab_kernel<<<MMGRID, 256, 65536, stream>>>(xb, pk + 0*16384, pk + 1*16384,
                                               eb1, 0, Ab, Bb, flag);
  for (int l = 0; l < 4; l++){
    const u16* NW1a = pk + (l*6+3)*16384;
    const u16* NW2p = pk + (l*6+5)*16384;
    const u16* W12p = pk + (24+l)*16384;
    float* pin  = (l & 1) ? pf1 : pf0;
    float* pout = (l & 1) ? pf0 : pf1;

    agg_kernel<<<(N+3)/4, 256, 0, stream>>>(
        rowptr, perm, pin, Ab, Bb,
        ew1, (long)l*257*128 + 256*128,
        w2p + l*128, c2p + l, pparm + l*4,
        Hb, pout, N, flag);
    mm_hidden_kernel<<<MMGRID, 256, 65536, stream>>>(
        xb, Hb, NW1a, W12p, nb1, (long)l*128, degf, ebW + l*128, hb, flag);
    if (l < 3){
      mm_res_kernel<0><<<RGRID, 256, 32768, stream>>>(
          hb, NW2p, nb2, (long)l*128, xb, nullptr, nullptr, nullptr, flag);
      mm_ab_kernel<<<MMGRID, 256, 65536, stream>>>(
          xb, pk + ((l+1)*6+0)*16384, pk + ((l+1)*6+1)*16384,
          eb1, (long)(l+1)*128, Ab, Bb, flag);
    } else {
      mm_res_kernel<1><<<RGRID, 256, 32768, stream>>>(
          hb, NW2p, nb2, (long)l*128, xb, lng, lnb, d_out, flag);
    }
  }
}